// Round 1
// baseline (4003.740 us; speedup 1.0000x reference)
//
#include <hip/hip_runtime.h>
#include <hip/hip_bf16.h>
#include <stdint.h>
#include <math.h>

using bf16 = __hip_bfloat16;
typedef __attribute__((ext_vector_type(8))) short short8;   // 8 x bf16 (4 VGPRs) — MFMA A/B frag
typedef __attribute__((ext_vector_type(4))) float f32x4;    // MFMA C/D frag

#define TOK    184320          // 16*96*120
#define CDIM   384
#define NWIN   2304            // 16*12*12
#define NTOK   80              // tokens per window
#define HEADS  12
#define BM     128
#define BK     64

// ---------------- ws layout (bytes) ----------------
constexpr size_t R0_SZ    = (size_t)TOK * CDIM * 2;           // 141,557,760 bf16 plane
constexpr size_t R0_OFF   = 0;                                 // y1 -> o -> y2 (sequential reuse)
constexpr size_t Q_OFF    = R0_SZ;                             // q  (also start of h reuse)
constexpr size_t K_OFF    = Q_OFF + R0_SZ;
constexpr size_t V_OFF    = K_OFF + R0_SZ;
constexpr size_t BIAS_OFF = V_OFF + R0_SZ;                     // 12*6400 f32 sigmoid bias
constexpr size_t WQKV_OFF = BIAS_OFF + (size_t)HEADS * 6400 * 4;
constexpr size_t WPROJ_OFF= WQKV_OFF + (size_t)1152 * 384 * 2;
constexpr size_t WGLU_OFF = WPROJ_OFF + (size_t)384 * 384 * 2;
constexpr size_t WOUT_OFF = WGLU_OFF + (size_t)2048 * 384 * 2;

// ---------------- helpers ----------------
__device__ __forceinline__ float b2f(unsigned short u) {
  return __uint_as_float(((unsigned)u) << 16);
}

__device__ __forceinline__ void gload_lds16(const void* g, void* l) {
  // async global->LDS, 16B/lane; LDS dest is wave-uniform base + lane*16
  typedef __attribute__((address_space(1))) char gchar;
  typedef __attribute__((address_space(3))) char lchar;
  __builtin_amdgcn_global_load_lds((gchar*)(uintptr_t)g, (lchar*)(uintptr_t)l, 16, 0, 0);
}

__device__ __forceinline__ int token_to_winrow(int t) {
  int b  = t / (96 * 120);
  int r  = t - b * (96 * 120);
  int hh = r / 120, ww = r - (r / 120) * 120;
  int win = b * 144 + (hh >> 3) * 12 + (ww / 10);
  int n   = (hh & 7) * 10 + (ww % 10);
  return win * NTOK + n;
}

__device__ __forceinline__ int winrow_to_token(int row) {
  int win = row / NTOK, n = row - win * NTOK;
  int b = win / 144, rem = win - b * 144;
  int hh = (rem / 12) * 8 + n / 10;
  int ww = (rem % 12) * 10 + n % 10;
  return (b * 96 + hh) * 120 + ww;
}

// ---------------- tiny kernels ----------------
__global__ void cvt_f32_bf16(const float* __restrict__ in, bf16* __restrict__ out, int n) {
  int i = blockIdx.x * 256 + threadIdx.x;
  if (i < n) out[i] = __float2bfloat16(in[i]);
}

// continuous rel-pos bias: relu(table @ w1^T + b1) @ w2^T, gather, 16*sigmoid
__global__ void cpb_bias_kernel(const float* __restrict__ w1, const float* __restrict__ b1,
                                const float* __restrict__ w2, float* __restrict__ bias16) {
  __shared__ float tab[285][12];
  for (int r = threadIdx.x; r < 285; r += blockDim.x) {
    int i = r / 19, j = r - (r / 19) * 19;
    float c0 = 8.0f * (float)(i - 7) / 7.0f;
    float c1 = 8.0f * (float)(j - 9) / 9.0f;
    const float inv3 = 1.0f / 3.0f;   // 1/log2(8)
    float t0 = (c0 >= 0.f ? 1.f : -1.f) * log2f(fabsf(c0) + 1.f) * inv3;
    float t1 = (c1 >= 0.f ? 1.f : -1.f) * log2f(fabsf(c1) + 1.f) * inv3;
    float acc[12];
    #pragma unroll
    for (int h = 0; h < 12; h++) acc[h] = 0.f;
    for (int k = 0; k < 512; k++) {
      float hk = fmaxf(w1[2 * k] * t0 + w1[2 * k + 1] * t1 + b1[k], 0.f);
      #pragma unroll
      for (int h = 0; h < 12; h++) acc[h] += hk * w2[h * 512 + k];
    }
    #pragma unroll
    for (int h = 0; h < 12; h++) tab[r][h] = acc[h];
  }
  __syncthreads();
  for (int e = threadIdx.x; e < 6400; e += blockDim.x) {
    int n = e / 80, m = e - n * 80;
    int id = (n / 10 - m / 10 + 7) * 19 + (n % 10 - m % 10 + 9);
    #pragma unroll
    for (int h = 0; h < 12; h++) {
      float t = tab[id][h];
      bias16[h * 6400 + e] = 16.0f / (1.0f + __expf(-t));
    }
  }
}

// layernorm over C=384, one wave per token; optional windowed row permutation on output
__global__ __launch_bounds__(256)
void ln_kernel(const float* __restrict__ x, const float* __restrict__ g,
               const float* __restrict__ b, bf16* __restrict__ out, int windowed) {
  const int wv = threadIdx.x >> 6, lane = threadIdx.x & 63;
  const int token = blockIdx.x * 4 + wv;
  const float* px = x + (size_t)token * CDIM;
  float v[6];
  float s = 0.f;
  #pragma unroll
  for (int j = 0; j < 6; j++) { v[j] = px[lane + 64 * j]; s += v[j]; }
  #pragma unroll
  for (int off = 32; off; off >>= 1) s += __shfl_xor(s, off);
  const float mean = s * (1.0f / 384.0f);
  float sq = 0.f;
  #pragma unroll
  for (int j = 0; j < 6; j++) { float d = v[j] - mean; sq += d * d; }
  #pragma unroll
  for (int off = 32; off; off >>= 1) sq += __shfl_xor(sq, off);
  const float rs = rsqrtf(sq * (1.0f / 384.0f) + 1e-5f);
  const int rowb = windowed ? token_to_winrow(token) : token;
  bf16* po = out + (size_t)rowb * CDIM;
  #pragma unroll
  for (int j = 0; j < 6; j++) {
    int c = lane + 64 * j;
    po[c] = __float2bfloat16((v[j] - mean) * rs * g[c] + b[c]);
  }
}

// ---------------- GEMM core (m97-style: 128x128 tile, BK=64, 4 waves, 2-barrier) ----------------
// A: row-major M x K (bf16). B: weight row-major N x K (bf16) -> computes A @ W^T.
__device__ __forceinline__ void gemm_core(const bf16* __restrict__ Ab, const bf16* __restrict__ Bb,
                                          int K, f32x4 acc[4][4], bf16* As, bf16* Bs) {
  const int tid = threadIdx.x;
  const int w = tid >> 6, lane = tid & 63;
  const int wr = w >> 1, wc = w & 1;
  const int lr = lane & 15, kg = lane >> 4;
  const f32x4 zero = {0.f, 0.f, 0.f, 0.f};
  #pragma unroll
  for (int m = 0; m < 4; m++)
    #pragma unroll
    for (int n = 0; n < 4; n++) acc[m][n] = zero;

  for (int kt = 0; kt < K; kt += BK) {
    #pragma unroll
    for (int i = 0; i < 4; i++) {
      const int chunk = i * 4 + w;                 // 16 chunks x 1024B per 128x64 tile
      const int elem  = chunk * 512 + lane * 8;    // this lane's 8 bf16
      const int r = elem >> 6, c = elem & 63;
      gload_lds16(Ab + (size_t)r * K + kt + c, As + chunk * 512);
      gload_lds16(Bb + (size_t)r * K + kt + c, Bs + chunk * 512);
    }
    __syncthreads();                                // drains vmcnt before barrier
    #pragma unroll
    for (int kk = 0; kk < BK; kk += 32) {
      short8 af[4], bfr[4];
      #pragma unroll
      for (int m = 0; m < 4; m++)
        af[m] = *(const short8*)(As + (wr * 64 + m * 16 + lr) * BK + kk + kg * 8);
      #pragma unroll
      for (int n = 0; n < 4; n++)
        bfr[n] = *(const short8*)(Bs + (wc * 64 + n * 16 + lr) * BK + kk + kg * 8);
      #pragma unroll
      for (int m = 0; m < 4; m++)
        #pragma unroll
        for (int n = 0; n < 4; n++)
          acc[m][n] = __builtin_amdgcn_mfma_f32_16x16x32_bf16(af[m], bfr[n], acc[m][n], 0, 0, 0);
    }
    __syncthreads();
  }
}

// QKV GEMM: rows already in windowed order; epilogue scatters to q/k/v [win][head][n][d] + bias
__global__ __launch_bounds__(256)
void gemm_qkv_kernel(const bf16* __restrict__ A, const bf16* __restrict__ W,
                     const float* __restrict__ qb, const float* __restrict__ vb,
                     bf16* __restrict__ qo, bf16* __restrict__ ko, bf16* __restrict__ vo) {
  __shared__ bf16 As[BM * BK], Bs[BM * BK];
  const int bx = blockIdx.x, by = blockIdx.y;
  f32x4 acc[4][4];
  gemm_core(A + (size_t)by * 128 * 384, W + (size_t)bx * 128 * 384, 384, acc, As, Bs);
  const int lane = threadIdx.x & 63, w = threadIdx.x >> 6;
  const int wr = w >> 1, wc = w & 1, lr = lane & 15, kg = lane >> 4;
  #pragma unroll
  for (int m = 0; m < 4; m++)
    #pragma unroll
    for (int i = 0; i < 4; i++) {
      const int row = by * 128 + wr * 64 + m * 16 + kg * 4 + i;
      const int win = row / NTOK, n = row - win * NTOK;
      #pragma unroll
      for (int nn = 0; nn < 4; nn++) {
        const int col = bx * 128 + wc * 64 + nn * 16 + lr;
        const int which = col / 384;
        const int c = col - which * 384;
        const int head = c >> 5, d = c & 31;
        const size_t idx = (((size_t)win * HEADS + head) * NTOK + n) * 32 + d;
        float val = acc[m][nn][i];
        if (which == 0)      qo[idx] = __float2bfloat16(val + qb[c]);
        else if (which == 2) vo[idx] = __float2bfloat16(val + vb[c]);
        else                 ko[idx] = __float2bfloat16(val);
      }
    }
}

// proj GEMM: epilogue reverses window permutation and writes x1 = x + ls1*(o@W^T+b) fp32 to d_out
__global__ __launch_bounds__(256)
void gemm_proj_kernel(const bf16* __restrict__ A, const bf16* __restrict__ W,
                      const float* __restrict__ pb, const float* __restrict__ x,
                      const float* __restrict__ ls1, float* __restrict__ out) {
  __shared__ bf16 As[BM * BK], Bs[BM * BK];
  const int bx = blockIdx.x, by = blockIdx.y;
  f32x4 acc[4][4];
  gemm_core(A + (size_t)by * 128 * 384, W + (size_t)bx * 128 * 384, 384, acc, As, Bs);
  const int lane = threadIdx.x & 63, w = threadIdx.x >> 6;
  const int wr = w >> 1, wc = w & 1, lr = lane & 15, kg = lane >> 4;
  #pragma unroll
  for (int m = 0; m < 4; m++)
    #pragma unroll
    for (int i = 0; i < 4; i++) {
      const int row = by * 128 + wr * 64 + m * 16 + kg * 4 + i;
      const int t = winrow_to_token(row);
      #pragma unroll
      for (int nn = 0; nn < 4; nn++) {
        const int col = bx * 128 + wc * 64 + nn * 16 + lr;
        const size_t gi = (size_t)t * CDIM + col;
        out[gi] = x[gi] + ls1[col] * (acc[m][nn][i] + pb[col]);
      }
    }
}

// fused GLU GEMM: computes both halves (a, gate) with two B tiles; h = a * gelu_exact(gate)
__global__ __launch_bounds__(256)
void gemm_glu_kernel(const bf16* __restrict__ A, const bf16* __restrict__ W,
                     const float* __restrict__ gb, bf16* __restrict__ h) {
  __shared__ bf16 As[BM * BK], Ba[BM * BK], Bg[BM * BK];
  const int bx = blockIdx.x, by = blockIdx.y;
  const bf16* Ab = A + (size_t)by * 128 * 384;
  const bf16* Wa = W + (size_t)(bx * 128) * 384;
  const bf16* Wg = W + (size_t)(1024 + bx * 128) * 384;
  const int tid = threadIdx.x;
  const int w = tid >> 6, lane = tid & 63;
  const int wr = w >> 1, wc = w & 1;
  const int lr = lane & 15, kg = lane >> 4;
  const f32x4 zero = {0.f, 0.f, 0.f, 0.f};
  f32x4 aA[4][4], aG[4][4];
  #pragma unroll
  for (int m = 0; m < 4; m++)
    #pragma unroll
    for (int n = 0; n < 4; n++) { aA[m][n] = zero; aG[m][n] = zero; }

  for (int kt = 0; kt < 384; kt += BK) {
    #pragma unroll
    for (int i = 0; i < 4; i++) {
      const int chunk = i * 4 + w;
      const int elem  = chunk * 512 + lane * 8;
      const int r = elem >> 6, c = elem & 63;
      gload_lds16(Ab + (size_t)r * 384 + kt + c, As + chunk * 512);
      gload_lds16(Wa + (size_t)r * 384 + kt + c, Ba + chunk * 512);
      gload_lds16(Wg + (size_t)r * 384 + kt + c, Bg + chunk * 512);
    }
    __syncthreads();
    #pragma unroll
    for (int kk = 0; kk < BK; kk += 32) {
      short8 af[4], ba[4], bg[4];
      #pragma unroll
      for (int m = 0; m < 4; m++)
        af[m] = *(const short8*)(As + (wr * 64 + m * 16 + lr) * BK + kk + kg * 8);
      #pragma unroll
      for (int n = 0; n < 4; n++) {
        ba[n] = *(const short8*)(Ba + (wc * 64 + n * 16 + lr) * BK + kk + kg * 8);
        bg[n] = *(const short8*)(Bg + (wc * 64 + n * 16 + lr) * BK + kk + kg * 8);
      }
      #pragma unroll
      for (int m = 0; m < 4; m++)
        #pragma unroll
        for (int n = 0; n < 4; n++) {
          aA[m][n] = __builtin_amdgcn_mfma_f32_16x16x32_bf16(af[m], ba[n], aA[m][n], 0, 0, 0);
          aG[m][n] = __builtin_amdgcn_mfma_f32_16x16x32_bf16(af[m], bg[n], aG[m][n], 0, 0, 0);
        }
    }
    __syncthreads();
  }
  #pragma unroll
  for (int m = 0; m < 4; m++)
    #pragma unroll
    for (int i = 0; i < 4; i++) {
      const int row = by * 128 + wr * 64 + m * 16 + kg * 4 + i;
      #pragma unroll
      for (int nn = 0; nn < 4; nn++) {
        const int col = bx * 128 + wc * 64 + nn * 16 + lr;
        float a = aA[m][nn][i] + gb[col];
        float g = aG[m][nn][i] + gb[1024 + col];
        float gelu = 0.5f * g * (1.0f + erff(g * 0.70710678118654752f));
        h[(size_t)row * 1024 + col] = __float2bfloat16(a * gelu);
      }
    }
}

// out GEMM: d_out += ls2 * (h @ W^T + b)  (token-major rows)
__global__ __launch_bounds__(256)
void gemm_out_kernel(const bf16* __restrict__ A, const bf16* __restrict__ W,
                     const float* __restrict__ ob, const float* __restrict__ ls2,
                     float* __restrict__ out) {
  __shared__ bf16 As[BM * BK], Bs[BM * BK];
  const int bx = blockIdx.x, by = blockIdx.y;
  f32x4 acc[4][4];
  gemm_core(A + (size_t)by * 128 * 1024, W + (size_t)bx * 128 * 1024, 1024, acc, As, Bs);
  const int lane = threadIdx.x & 63, w = threadIdx.x >> 6;
  const int wr = w >> 1, wc = w & 1, lr = lane & 15, kg = lane >> 4;
  #pragma unroll
  for (int m = 0; m < 4; m++)
    #pragma unroll
    for (int i = 0; i < 4; i++) {
      const int row = by * 128 + wr * 64 + m * 16 + kg * 4 + i;
      #pragma unroll
      for (int nn = 0; nn < 4; nn++) {
        const int col = bx * 128 + wc * 64 + nn * 16 + lr;
        const size_t gi = (size_t)row * CDIM + col;
        out[gi] += ls2[col] * (acc[m][nn][i] + ob[col]);
      }
    }
}

// ---------------- attention: one block per (window, head), vector fp32 ----------------
__global__ __launch_bounds__(256)
void attn_kernel(const bf16* __restrict__ q, const bf16* __restrict__ k,
                 const bf16* __restrict__ v, const float* __restrict__ bias16,
                 bf16* __restrict__ o) {
  __shared__ float qs[80][33], ks[80][33], vs[80][33];
  __shared__ float Ss[80][81];
  const int tid = threadIdx.x;
  const int wh = blockIdx.x;                 // win*12 + head
  const int win = wh / HEADS, head = wh - win * HEADS;
  const size_t base = (size_t)wh * (NTOK * 32);
  const ushort4* qg = (const ushort4*)((const unsigned short*)q + base);
  const ushort4* kg4 = (const ushort4*)((const unsigned short*)k + base);
  const ushort4* vg = (const ushort4*)((const unsigned short*)v + base);
  for (int i = tid; i < 640; i += 256) {
    ushort4 a = qg[i], b = kg4[i], c = vg[i];
    int n = (i * 4) >> 5, d = (i * 4) & 31;
    qs[n][d] = b2f(a.x); qs[n][d + 1] = b2f(a.y); qs[n][d + 2] = b2f(a.z); qs[n][d + 3] = b2f(a.w);
    ks[n][d] = b2f(b.x); ks[n][d + 1] = b2f(b.y); ks[n][d + 2] = b2f(b.z); ks[n][d + 3] = b2f(b.w);
    vs[n][d] = b2f(c.x); vs[n][d + 1] = b2f(c.y); vs[n][d + 2] = b2f(c.z); vs[n][d + 3] = b2f(c.w);
  }
  __syncthreads();
  if (tid < 160) {                           // L2-normalize q and k rows (eps 5e-5 on the norm)
    int r = (tid < 80) ? tid : tid - 80;
    float* row = (tid < 80) ? qs[r] : ks[r];
    float s = 0.f;
    #pragma unroll
    for (int d = 0; d < 32; d++) s += row[d] * row[d];
    float sc = 1.0f / (sqrtf(s) + 5e-5f);
    #pragma unroll
    for (int d = 0; d < 32; d++) row[d] *= sc;
  }
  __syncthreads();
  const float* bh = bias16 + head * 6400;
  for (int e = tid; e < 6400; e += 256) {    // S = q @ k^T + 16*sigmoid(bias)
    int n = e / 80, m = e - (e / 80) * 80;
    float s = 0.f;
    #pragma unroll
    for (int d = 0; d < 32; d++) s += qs[n][d] * ks[m][d];
    Ss[n][m] = s + bh[e];
  }
  __syncthreads();
  if (tid < 80) {                            // row softmax
    float mx = -1e30f;
    for (int m = 0; m < 80; m++) mx = fmaxf(mx, Ss[tid][m]);
    float sum = 0.f;
    for (int m = 0; m < 80; m++) { float e = __expf(Ss[tid][m] - mx); Ss[tid][m] = e; sum += e; }
    float inv = 1.0f / sum;
    for (int m = 0; m < 80; m++) Ss[tid][m] *= inv;
  }
  __syncthreads();
  bf16* ob = o + (size_t)win * NTOK * CDIM + head * 32;
  for (int e = tid; e < 2560; e += 256) {    // O = P @ V, write windowed-row layout
    int n = e >> 5, d = e & 31;
    float s = 0.f;
    for (int m = 0; m < 80; m++) s += Ss[n][m] * vs[m][d];
    ob[(size_t)n * CDIM + d] = __float2bfloat16(s);
  }
}

// ---------------- launcher ----------------
extern "C" void kernel_launch(void* const* d_in, const int* in_sizes, int n_in,
                              void* d_out, int out_size, void* d_ws, size_t ws_size,
                              hipStream_t stream) {
  const float* x       = (const float*)d_in[0];
  const float* n1g     = (const float*)d_in[1];
  const float* n1b     = (const float*)d_in[2];
  const float* qkv_w   = (const float*)d_in[3];
  const float* q_bias  = (const float*)d_in[4];
  const float* v_bias  = (const float*)d_in[5];
  const float* cpb_w1  = (const float*)d_in[6];
  const float* cpb_b1  = (const float*)d_in[7];
  const float* cpb_w2  = (const float*)d_in[8];
  const float* proj_w  = (const float*)d_in[9];
  const float* proj_b  = (const float*)d_in[10];
  const float* ls1     = (const float*)d_in[11];
  const float* n2g     = (const float*)d_in[12];
  const float* n2b     = (const float*)d_in[13];
  const float* glu_w   = (const float*)d_in[14];
  const float* glu_b   = (const float*)d_in[15];
  const float* out_w   = (const float*)d_in[16];
  const float* out_b   = (const float*)d_in[17];
  const float* ls2     = (const float*)d_in[18];
  float* out = (float*)d_out;

  char* ws = (char*)d_ws;
  bf16* r0     = (bf16*)(ws + R0_OFF);     // y1 -> o -> y2
  bf16* q_buf  = (bf16*)(ws + Q_OFF);
  bf16* k_buf  = (bf16*)(ws + K_OFF);
  bf16* v_buf  = (bf16*)(ws + V_OFF);
  bf16* h_buf  = (bf16*)(ws + Q_OFF);      // reuse qkv region after attention
  float* bias16 = (float*)(ws + BIAS_OFF);
  bf16* wqkv   = (bf16*)(ws + WQKV_OFF);
  bf16* wproj  = (bf16*)(ws + WPROJ_OFF);
  bf16* wglu   = (bf16*)(ws + WGLU_OFF);
  bf16* wout   = (bf16*)(ws + WOUT_OFF);

  // weight casts f32 -> bf16
  cvt_f32_bf16<<<dim3((1152 * 384 + 255) / 256), 256, 0, stream>>>(qkv_w, wqkv, 1152 * 384);
  cvt_f32_bf16<<<dim3((384 * 384 + 255) / 256), 256, 0, stream>>>(proj_w, wproj, 384 * 384);
  cvt_f32_bf16<<<dim3((2048 * 384 + 255) / 256), 256, 0, stream>>>(glu_w, wglu, 2048 * 384);
  cvt_f32_bf16<<<dim3((384 * 1024 + 255) / 256), 256, 0, stream>>>(out_w, wout, 384 * 1024);

  // rel-pos bias table (single block)
  cpb_bias_kernel<<<1, 256, 0, stream>>>(cpb_w1, cpb_b1, cpb_w2, bias16);

  // LN1 -> bf16, windowed row order
  ln_kernel<<<TOK / 4, 256, 0, stream>>>(x, n1g, n1b, r0, 1);

  // QKV GEMM (M=184320, N=1152, K=384)
  gemm_qkv_kernel<<<dim3(9, TOK / 128), 256, 0, stream>>>(r0, wqkv, q_bias, v_bias,
                                                          q_buf, k_buf, v_buf);

  // attention per (window, head); writes o into r0 (y1 dead)
  attn_kernel<<<NWIN * HEADS, 256, 0, stream>>>(q_buf, k_buf, v_buf, bias16, r0);

  // proj GEMM + window-reverse + x1 = x + ls1*o  -> d_out (fp32)
  gemm_proj_kernel<<<dim3(3, TOK / 128), 256, 0, stream>>>(r0, wproj, proj_b, x, ls1, out);

  // LN2 (token-major) -> r0 as y2
  ln_kernel<<<TOK / 4, 256, 0, stream>>>(out, n2g, n2b, r0, 0);

  // fused GLU GEMM (M=184320, N=1024 output, K=384, both halves) -> h
  gemm_glu_kernel<<<dim3(8, TOK / 128), 256, 0, stream>>>(r0, wglu, glu_b, h_buf);

  // out GEMM (M=184320, N=384, K=1024), d_out += ls2*(h@W^T + b)
  gemm_out_kernel<<<dim3(3, TOK / 128), 256, 0, stream>>>(h_buf, wout, out_b, ls2, out);

  (void)in_sizes; (void)n_in; (void)out_size; (void)ws_size;
}

// Round 2
// 3164.033 us; speedup vs baseline: 1.2654x; 1.2654x over previous
//
#include <hip/hip_runtime.h>
#include <hip/hip_bf16.h>
#include <stdint.h>
#include <math.h>

using bf16 = __hip_bfloat16;
typedef __attribute__((ext_vector_type(8))) short short8;   // 8 x bf16 (4 VGPRs) — MFMA A/B frag
typedef __attribute__((ext_vector_type(4))) short short4b;  // 4 x bf16 (8B)
typedef __attribute__((ext_vector_type(4))) float f32x4;    // MFMA C/D frag

#define TOK    184320          // 16*96*120
#define CDIM   384
#define NWIN   2304            // 16*12*12
#define NTOK   80              // tokens per window
#define HEADS  12
#define BM     128
#define BK     64

// ---------------- ws layout (bytes) ----------------
constexpr size_t R0_SZ    = (size_t)TOK * CDIM * 2;           // 141,557,760 bf16 plane
constexpr size_t R0_OFF   = 0;                                 // y1 -> vT -> y2
constexpr size_t Q_OFF    = R0_SZ;                             // q  (also start of h reuse)
constexpr size_t K_OFF    = Q_OFF + R0_SZ;
constexpr size_t V_OFF    = K_OFF + R0_SZ;                     // v -> O (attn output)
constexpr size_t BIAS_OFF = V_OFF + R0_SZ;                     // 12*6400 f32 sigmoid biasT
constexpr size_t WQKV_OFF = BIAS_OFF + (size_t)HEADS * 6400 * 4;
constexpr size_t WPROJ_OFF= WQKV_OFF + (size_t)1152 * 384 * 2;
constexpr size_t WGLU_OFF = WPROJ_OFF + (size_t)384 * 384 * 2;
constexpr size_t WOUT_OFF = WGLU_OFF + (size_t)2048 * 384 * 2;

// ---------------- helpers ----------------
__device__ __forceinline__ float b2f(unsigned short u) {
  return __uint_as_float(((unsigned)u) << 16);
}
__device__ __forceinline__ short f2bs(float x) {
  return (short)__bfloat16_as_ushort(__float2bfloat16(x));
}

__device__ __forceinline__ void gload_lds16(const void* g, void* l) {
  typedef __attribute__((address_space(1))) char gchar;
  typedef __attribute__((address_space(3))) char lchar;
  __builtin_amdgcn_global_load_lds((gchar*)(uintptr_t)g, (lchar*)(uintptr_t)l, 16, 0, 0);
}

__device__ __forceinline__ int token_to_winrow(int t) {
  int b  = t / (96 * 120);
  int r  = t - b * (96 * 120);
  int hh = r / 120, ww = r - (r / 120) * 120;
  int win = b * 144 + (hh >> 3) * 12 + (ww / 10);
  int n   = (hh & 7) * 10 + (ww % 10);
  return win * NTOK + n;
}

__device__ __forceinline__ int winrow_to_token(int row) {
  int win = row / NTOK, n = row - win * NTOK;
  int b = win / 144, rem = win - b * 144;
  int hh = (rem / 12) * 8 + n / 10;
  int ww = (rem % 12) * 10 + n % 10;
  return (b * 96 + hh) * 120 + ww;
}

// ---------------- tiny kernels ----------------
__global__ void cvt_f32_bf16(const float* __restrict__ in, bf16* __restrict__ out, int n) {
  int i = blockIdx.x * 256 + threadIdx.x;
  if (i < n) out[i] = __float2bfloat16(in[i]);
}

// continuous rel-pos bias, TRANSPOSED output: biasT[h][k*80+q] = 16*sigmoid(mlp(table)[idx[q][k]][h])
__global__ void cpb_bias_kernel(const float* __restrict__ w1, const float* __restrict__ b1,
                                const float* __restrict__ w2, float* __restrict__ biasT) {
  __shared__ float tab[285][12];
  for (int r = threadIdx.x; r < 285; r += blockDim.x) {
    int i = r / 19, j = r - (r / 19) * 19;
    float c0 = 8.0f * (float)(i - 7) / 7.0f;
    float c1 = 8.0f * (float)(j - 9) / 9.0f;
    const float inv3 = 1.0f / 3.0f;   // 1/log2(8)
    float t0 = (c0 >= 0.f ? 1.f : -1.f) * log2f(fabsf(c0) + 1.f) * inv3;
    float t1 = (c1 >= 0.f ? 1.f : -1.f) * log2f(fabsf(c1) + 1.f) * inv3;
    float acc[12];
    #pragma unroll
    for (int h = 0; h < 12; h++) acc[h] = 0.f;
    for (int k = 0; k < 512; k++) {
      float hk = fmaxf(w1[2 * k] * t0 + w1[2 * k + 1] * t1 + b1[k], 0.f);
      #pragma unroll
      for (int h = 0; h < 12; h++) acc[h] += hk * w2[h * 512 + k];
    }
    #pragma unroll
    for (int h = 0; h < 12; h++) tab[r][h] = acc[h];
  }
  __syncthreads();
  for (int e = threadIdx.x; e < 6400; e += blockDim.x) {
    int n = e / 80, m = e - (e / 80) * 80;   // n = q index, m = k index
    int id = (n / 10 - m / 10 + 7) * 19 + (n % 10 - m % 10 + 9);
    #pragma unroll
    for (int h = 0; h < 12; h++) {
      float t = tab[id][h];
      biasT[h * 6400 + m * 80 + n] = 16.0f / (1.0f + __expf(-t));
    }
  }
}

// layernorm over C=384, one wave per token; optional windowed row permutation on output
__global__ __launch_bounds__(256)
void ln_kernel(const float* __restrict__ x, const float* __restrict__ g,
               const float* __restrict__ b, bf16* __restrict__ out, int windowed) {
  const int wv = threadIdx.x >> 6, lane = threadIdx.x & 63;
  const int token = blockIdx.x * 4 + wv;
  const float* px = x + (size_t)token * CDIM;
  float v[6];
  float s = 0.f;
  #pragma unroll
  for (int j = 0; j < 6; j++) { v[j] = px[lane + 64 * j]; s += v[j]; }
  #pragma unroll
  for (int off = 32; off; off >>= 1) s += __shfl_xor(s, off);
  const float mean = s * (1.0f / 384.0f);
  float sq = 0.f;
  #pragma unroll
  for (int j = 0; j < 6; j++) { float d = v[j] - mean; sq += d * d; }
  #pragma unroll
  for (int off = 32; off; off >>= 1) sq += __shfl_xor(sq, off);
  const float rs = rsqrtf(sq * (1.0f / 384.0f) + 1e-5f);
  const int rowb = windowed ? token_to_winrow(token) : token;
  bf16* po = out + (size_t)rowb * CDIM;
  #pragma unroll
  for (int j = 0; j < 6; j++) {
    int c = lane + 64 * j;
    po[c] = __float2bfloat16((v[j] - mean) * rs * g[c] + b[c]);
  }
}

// V transpose: v[wh][80][32] -> vT[wh][32][80]
__global__ __launch_bounds__(64)
void vtrans_kernel(const bf16* __restrict__ v, bf16* __restrict__ vT) {
  __shared__ unsigned short vt[32][82];
  const int wh = blockIdx.x, t = threadIdx.x;
  const unsigned short* vg = (const unsigned short*)v + (size_t)wh * 2560;
  #pragma unroll
  for (int j = 0; j < 5; j++) {
    int c = (t + 64 * j) * 8;                 // elem base, 0..2552
    short8 u = *(const short8*)(vg + c);
    int n = c >> 5, d = c & 31;
    #pragma unroll
    for (int e = 0; e < 8; e++) vt[d + e][n] = (unsigned short)u[e];
  }
  __syncthreads();
  unsigned int* og = (unsigned int*)((unsigned short*)vT + (size_t)wh * 2560);
  #pragma unroll
  for (int j = 0; j < 20; j++) {
    int p = t + 64 * j;                        // uint index 0..1279
    int e = p * 2;
    int d = e / 80, kcol = e - (e / 80) * 80;  // 80 even -> pair within row
    og[p] = (unsigned int)vt[d][kcol] | ((unsigned int)vt[d][kcol + 1] << 16);
  }
}

// ---------------- GEMM core (m97-style: 128x128 tile, BK=64, 4 waves, 2-barrier) ----------------
__device__ __forceinline__ void gemm_core(const bf16* __restrict__ Ab, const bf16* __restrict__ Bb,
                                          int K, f32x4 acc[4][4], bf16* As, bf16* Bs) {
  const int tid = threadIdx.x;
  const int w = tid >> 6, lane = tid & 63;
  const int wr = w >> 1, wc = w & 1;
  const int lr = lane & 15, kg = lane >> 4;
  const f32x4 zero = {0.f, 0.f, 0.f, 0.f};
  #pragma unroll
  for (int m = 0; m < 4; m++)
    #pragma unroll
    for (int n = 0; n < 4; n++) acc[m][n] = zero;

  for (int kt = 0; kt < K; kt += BK) {
    #pragma unroll
    for (int i = 0; i < 4; i++) {
      const int chunk = i * 4 + w;
      const int elem  = chunk * 512 + lane * 8;
      const int r = elem >> 6, c = elem & 63;
      gload_lds16(Ab + (size_t)r * K + kt + c, As + chunk * 512);
      gload_lds16(Bb + (size_t)r * K + kt + c, Bs + chunk * 512);
    }
    __syncthreads();
    #pragma unroll
    for (int kk = 0; kk < BK; kk += 32) {
      short8 af[4], bfr[4];
      #pragma unroll
      for (int m = 0; m < 4; m++)
        af[m] = *(const short8*)(As + (wr * 64 + m * 16 + lr) * BK + kk + kg * 8);
      #pragma unroll
      for (int n = 0; n < 4; n++)
        bfr[n] = *(const short8*)(Bs + (wc * 64 + n * 16 + lr) * BK + kk + kg * 8);
      #pragma unroll
      for (int m = 0; m < 4; m++)
        #pragma unroll
        for (int n = 0; n < 4; n++)
          acc[m][n] = __builtin_amdgcn_mfma_f32_16x16x32_bf16(af[m], bfr[n], acc[m][n], 0, 0, 0);
    }
    __syncthreads();
  }
}

// QKV GEMM epilogue: scatter to q/k/v [win][head][n][d] + bias
__global__ __launch_bounds__(256)
void gemm_qkv_kernel(const bf16* __restrict__ A, const bf16* __restrict__ W,
                     const float* __restrict__ qb, const float* __restrict__ vb,
                     bf16* __restrict__ qo, bf16* __restrict__ ko, bf16* __restrict__ vo) {
  __shared__ bf16 As[BM * BK], Bs[BM * BK];
  const int bx = blockIdx.x, by = blockIdx.y;
  f32x4 acc[4][4];
  gemm_core(A + (size_t)by * 128 * 384, W + (size_t)bx * 128 * 384, 384, acc, As, Bs);
  const int lane = threadIdx.x & 63, w = threadIdx.x >> 6;
  const int wr = w >> 1, wc = w & 1, lr = lane & 15, kg = lane >> 4;
  #pragma unroll
  for (int m = 0; m < 4; m++)
    #pragma unroll
    for (int i = 0; i < 4; i++) {
      const int row = by * 128 + wr * 64 + m * 16 + kg * 4 + i;
      const int win = row / NTOK, n = row - win * NTOK;
      #pragma unroll
      for (int nn = 0; nn < 4; nn++) {
        const int col = bx * 128 + wc * 64 + nn * 16 + lr;
        const int which = col / 384;
        const int c = col - which * 384;
        const int head = c >> 5, d = c & 31;
        const size_t idx = (((size_t)win * HEADS + head) * NTOK + n) * 32 + d;
        float val = acc[m][nn][i];
        if (which == 0)      qo[idx] = __float2bfloat16(val + qb[c]);
        else if (which == 2) vo[idx] = __float2bfloat16(val + vb[c]);
        else                 ko[idx] = __float2bfloat16(val);
      }
    }
}

// proj GEMM: epilogue reverses window permutation and writes x1 = x + ls1*(o@W^T+b) fp32
__global__ __launch_bounds__(256)
void gemm_proj_kernel(const bf16* __restrict__ A, const bf16* __restrict__ W,
                      const float* __restrict__ pb, const float* __restrict__ x,
                      const float* __restrict__ ls1, float* __restrict__ out) {
  __shared__ bf16 As[BM * BK], Bs[BM * BK];
  const int bx = blockIdx.x, by = blockIdx.y;
  f32x4 acc[4][4];
  gemm_core(A + (size_t)by * 128 * 384, W + (size_t)bx * 128 * 384, 384, acc, As, Bs);
  const int lane = threadIdx.x & 63, w = threadIdx.x >> 6;
  const int wr = w >> 1, wc = w & 1, lr = lane & 15, kg = lane >> 4;
  #pragma unroll
  for (int m = 0; m < 4; m++)
    #pragma unroll
    for (int i = 0; i < 4; i++) {
      const int row = by * 128 + wr * 64 + m * 16 + kg * 4 + i;
      const int t = winrow_to_token(row);
      #pragma unroll
      for (int nn = 0; nn < 4; nn++) {
        const int col = bx * 128 + wc * 64 + nn * 16 + lr;
        const size_t gi = (size_t)t * CDIM + col;
        out[gi] = x[gi] + ls1[col] * (acc[m][nn][i] + pb[col]);
      }
    }
}

// fused GLU GEMM
__global__ __launch_bounds__(256)
void gemm_glu_kernel(const bf16* __restrict__ A, const bf16* __restrict__ W,
                     const float* __restrict__ gb, bf16* __restrict__ h) {
  __shared__ bf16 As[BM * BK], Ba[BM * BK], Bg[BM * BK];
  const int bx = blockIdx.x, by = blockIdx.y;
  const bf16* Ab = A + (size_t)by * 128 * 384;
  const bf16* Wa = W + (size_t)(bx * 128) * 384;
  const bf16* Wg = W + (size_t)(1024 + bx * 128) * 384;
  const int tid = threadIdx.x;
  const int w = tid >> 6, lane = tid & 63;
  const int wr = w >> 1, wc = w & 1;
  const int lr = lane & 15, kg = lane >> 4;
  const f32x4 zero = {0.f, 0.f, 0.f, 0.f};
  f32x4 aA[4][4], aG[4][4];
  #pragma unroll
  for (int m = 0; m < 4; m++)
    #pragma unroll
    for (int n = 0; n < 4; n++) { aA[m][n] = zero; aG[m][n] = zero; }

  for (int kt = 0; kt < 384; kt += BK) {
    #pragma unroll
    for (int i = 0; i < 4; i++) {
      const int chunk = i * 4 + w;
      const int elem  = chunk * 512 + lane * 8;
      const int r = elem >> 6, c = elem & 63;
      gload_lds16(Ab + (size_t)r * 384 + kt + c, As + chunk * 512);
      gload_lds16(Wa + (size_t)r * 384 + kt + c, Ba + chunk * 512);
      gload_lds16(Wg + (size_t)r * 384 + kt + c, Bg + chunk * 512);
    }
    __syncthreads();
    #pragma unroll
    for (int kk = 0; kk < BK; kk += 32) {
      short8 af[4], ba[4], bg[4];
      #pragma unroll
      for (int m = 0; m < 4; m++)
        af[m] = *(const short8*)(As + (wr * 64 + m * 16 + lr) * BK + kk + kg * 8);
      #pragma unroll
      for (int n = 0; n < 4; n++) {
        ba[n] = *(const short8*)(Ba + (wc * 64 + n * 16 + lr) * BK + kk + kg * 8);
        bg[n] = *(const short8*)(Bg + (wc * 64 + n * 16 + lr) * BK + kk + kg * 8);
      }
      #pragma unroll
      for (int m = 0; m < 4; m++)
        #pragma unroll
        for (int n = 0; n < 4; n++) {
          aA[m][n] = __builtin_amdgcn_mfma_f32_16x16x32_bf16(af[m], ba[n], aA[m][n], 0, 0, 0);
          aG[m][n] = __builtin_amdgcn_mfma_f32_16x16x32_bf16(af[m], bg[n], aG[m][n], 0, 0, 0);
        }
    }
    __syncthreads();
  }
  #pragma unroll
  for (int m = 0; m < 4; m++)
    #pragma unroll
    for (int i = 0; i < 4; i++) {
      const int row = by * 128 + wr * 64 + m * 16 + kg * 4 + i;
      #pragma unroll
      for (int nn = 0; nn < 4; nn++) {
        const int col = bx * 128 + wc * 64 + nn * 16 + lr;
        float a = aA[m][nn][i] + gb[col];
        float g = aG[m][nn][i] + gb[1024 + col];
        float gelu = 0.5f * g * (1.0f + erff(g * 0.70710678118654752f));
        h[(size_t)row * 1024 + col] = __float2bfloat16(a * gelu);
      }
    }
}

// out GEMM: d_out += ls2 * (h @ W^T + b)
__global__ __launch_bounds__(256)
void gemm_out_kernel(const bf16* __restrict__ A, const bf16* __restrict__ W,
                     const float* __restrict__ ob, const float* __restrict__ ls2,
                     float* __restrict__ out) {
  __shared__ bf16 As[BM * BK], Bs[BM * BK];
  const int bx = blockIdx.x, by = blockIdx.y;
  f32x4 acc[4][4];
  gemm_core(A + (size_t)by * 128 * 1024, W + (size_t)bx * 128 * 1024, 1024, acc, As, Bs);
  const int lane = threadIdx.x & 63, w = threadIdx.x >> 6;
  const int wr = w >> 1, wc = w & 1, lr = lane & 15, kg = lane >> 4;
  #pragma unroll
  for (int m = 0; m < 4; m++)
    #pragma unroll
    for (int i = 0; i < 4; i++) {
      const int row = by * 128 + wr * 64 + m * 16 + kg * 4 + i;
      #pragma unroll
      for (int nn = 0; nn < 4; nn++) {
        const int col = bx * 128 + wc * 64 + nn * 16 + lr;
        const size_t gi = (size_t)row * CDIM + col;
        out[gi] += ls2[col] * (acc[m][nn][i] + ob[col]);
      }
    }
}

// ---------------- MFMA attention: block = window, 4 waves x 3 heads, no barriers ----------------
// S^T = mfma(K, Q): lane holds q-col = lane&15, k-rows in regs -> softmax mostly in-register.
// P (q x k, /sum, bf16) -> per-wave LDS (stride 104, k 80..95 zeroed) -> PV via mfma(P, V^T).
__global__ __launch_bounds__(256, 2)
void attn_kernel(const bf16* __restrict__ q, const bf16* __restrict__ k,
                 const bf16* __restrict__ vT, const float* __restrict__ biasT,
                 bf16* __restrict__ o) {
  __shared__ short P_all[4][80 * 104];
  const int wv = threadIdx.x >> 6, lane = threadIdx.x & 63;
  const int lr = lane & 15, kg = lane >> 4;
  const int win = blockIdx.x;
  short* P = &P_all[wv][0];
  // zero pad cols 80..95 (persistent across heads; P writes only touch k<80)
  #pragma unroll
  for (int j = 0; j < 10; j++) {
    int idx = lane + 64 * j;          // 0..639
    int r = idx >> 3, c = idx & 7;
    *(int*)(P + r * 104 + 80 + c * 2) = 0;
  }
  for (int hh = 0; hh < 3; hh++) {
    const int head = wv * 3 + hh;
    const size_t hb = ((size_t)win * HEADS + head) * 2560;
    // load Q,K fragments (row = tile*16+lr, elems d = kg*8..+8) and L2-normalize rows
    short8 qf[5], kf[5];
    #pragma unroll
    for (int t5 = 0; t5 < 5; t5++) {
      const int roff = (t5 * 16 + lr) * 32 + kg * 8;
      {
        short8 u = *(const short8*)((const unsigned short*)q + hb + roff);
        float f[8]; float s = 0.f;
        #pragma unroll
        for (int j2 = 0; j2 < 8; j2++) { float x = b2f((unsigned short)u[j2]); f[j2] = x; s += x * x; }
        s += __shfl_xor(s, 16); s += __shfl_xor(s, 32);
        float sc = 1.0f / (sqrtf(s) + 5e-5f);
        short8 r8;
        #pragma unroll
        for (int j2 = 0; j2 < 8; j2++) r8[j2] = f2bs(f[j2] * sc);
        qf[t5] = r8;
      }
      {
        short8 u = *(const short8*)((const unsigned short*)k + hb + roff);
        float f[8]; float s = 0.f;
        #pragma unroll
        for (int j2 = 0; j2 < 8; j2++) { float x = b2f((unsigned short)u[j2]); f[j2] = x; s += x * x; }
        s += __shfl_xor(s, 16); s += __shfl_xor(s, 32);
        float sc = 1.0f / (sqrtf(s) + 5e-5f);
        short8 r8;
        #pragma unroll
        for (int j2 = 0; j2 < 8; j2++) r8[j2] = f2bs(f[j2] * sc);
        kf[t5] = r8;
      }
    }
    // S^T tiles: st[ki][qi], D rows = k, cols = q
    f32x4 st[5][5];
    #pragma unroll
    for (int a = 0; a < 5; a++)
      #pragma unroll
      for (int b = 0; b < 5; b++) st[a][b] = (f32x4){0.f, 0.f, 0.f, 0.f};
    #pragma unroll
    for (int a = 0; a < 5; a++)
      #pragma unroll
      for (int b = 0; b < 5; b++)
        st[a][b] = __builtin_amdgcn_mfma_f32_16x16x32_bf16(kf[a], qf[b], st[a][b], 0, 0, 0);
    // + bias (transposed table: [k][q], coalesced per 16-lane group)
    const float* bh = biasT + head * 6400;
    #pragma unroll
    for (int a = 0; a < 5; a++)
      #pragma unroll
      for (int b = 0; b < 5; b++)
        #pragma unroll
        for (int i = 0; i < 4; i++)
          st[a][b][i] += bh[(a * 16 + kg * 4 + i) * 80 + b * 16 + lr];
    // softmax over k per q-column; k spread over {a,i} regs x kg lane groups
    float inv[5];
    #pragma unroll
    for (int b = 0; b < 5; b++) {
      float mx = -1e30f;
      #pragma unroll
      for (int a = 0; a < 5; a++)
        #pragma unroll
        for (int i = 0; i < 4; i++) mx = fmaxf(mx, st[a][b][i]);
      mx = fmaxf(mx, __shfl_xor(mx, 16));
      mx = fmaxf(mx, __shfl_xor(mx, 32));
      float sm = 0.f;
      #pragma unroll
      for (int a = 0; a < 5; a++)
        #pragma unroll
        for (int i = 0; i < 4; i++) { float e = __expf(st[a][b][i] - mx); st[a][b][i] = e; sm += e; }
      sm += __shfl_xor(sm, 16); sm += __shfl_xor(sm, 32);
      inv[b] = 1.0f / sm;
    }
    // write P[q][k] bf16 (pre-divided by sum); q = b*16+lr, k = a*16+kg*4+i (i consecutive -> b64)
    #pragma unroll
    for (int a = 0; a < 5; a++)
      #pragma unroll
      for (int b = 0; b < 5; b++) {
        short4b pk;
        #pragma unroll
        for (int i = 0; i < 4; i++) pk[i] = f2bs(st[a][b][i] * inv[b]);
        *(short4b*)(P + (b * 16 + lr) * 104 + a * 16 + kg * 4) = pk;
      }
    // PV: O[q][d] = sum_k P[q][k] V^T[d][k]; K-steps 32/32/16(+zero pad)
    const unsigned short* vh = (const unsigned short*)vT + hb;   // [32][80]
    short8 vf[2][3];
    #pragma unroll
    for (int dt = 0; dt < 2; dt++)
      #pragma unroll
      for (int ks = 0; ks < 3; ks++) {
        const int kb = ks * 32 + ((ks == 2 && kg >= 2) ? 0 : kg * 8);  // clamp: P pad is zero there
        vf[dt][ks] = *(const short8*)(vh + (dt * 16 + lr) * 80 + kb);
      }
    f32x4 oc[5][2];
    #pragma unroll
    for (int b = 0; b < 5; b++)
      #pragma unroll
      for (int dt = 0; dt < 2; dt++) oc[b][dt] = (f32x4){0.f, 0.f, 0.f, 0.f};
    #pragma unroll
    for (int b = 0; b < 5; b++) {
      short8 pa[3];
      #pragma unroll
      for (int ks = 0; ks < 3; ks++)
        pa[ks] = *(const short8*)(P + (b * 16 + lr) * 104 + ks * 32 + kg * 8);
      #pragma unroll
      for (int dt = 0; dt < 2; dt++)
        #pragma unroll
        for (int ks = 0; ks < 3; ks++)
          oc[b][dt] = __builtin_amdgcn_mfma_f32_16x16x32_bf16(pa[ks], vf[dt][ks], oc[b][dt], 0, 0, 0);
    }
    // store O (windowed row layout)
    unsigned short* ob = (unsigned short*)o + (size_t)win * NTOK * CDIM + head * 32;
    #pragma unroll
    for (int b = 0; b < 5; b++)
      #pragma unroll
      for (int i = 0; i < 4; i++) {
        const int row = b * 16 + kg * 4 + i;
        #pragma unroll
        for (int dt = 0; dt < 2; dt++)
          ob[(size_t)row * CDIM + dt * 16 + lr] = (unsigned short)f2bs(oc[b][dt][i]);
      }
  }
}

// ---------------- launcher ----------------
extern "C" void kernel_launch(void* const* d_in, const int* in_sizes, int n_in,
                              void* d_out, int out_size, void* d_ws, size_t ws_size,
                              hipStream_t stream) {
  const float* x       = (const float*)d_in[0];
  const float* n1g     = (const float*)d_in[1];
  const float* n1b     = (const float*)d_in[2];
  const float* qkv_w   = (const float*)d_in[3];
  const float* q_bias  = (const float*)d_in[4];
  const float* v_bias  = (const float*)d_in[5];
  const float* cpb_w1  = (const float*)d_in[6];
  const float* cpb_b1  = (const float*)d_in[7];
  const float* cpb_w2  = (const float*)d_in[8];
  const float* proj_w  = (const float*)d_in[9];
  const float* proj_b  = (const float*)d_in[10];
  const float* ls1     = (const float*)d_in[11];
  const float* n2g     = (const float*)d_in[12];
  const float* n2b     = (const float*)d_in[13];
  const float* glu_w   = (const float*)d_in[14];
  const float* glu_b   = (const float*)d_in[15];
  const float* out_w   = (const float*)d_in[16];
  const float* out_b   = (const float*)d_in[17];
  const float* ls2     = (const float*)d_in[18];
  float* out = (float*)d_out;

  char* ws = (char*)d_ws;
  bf16* r0     = (bf16*)(ws + R0_OFF);     // y1 -> vT -> y2
  bf16* q_buf  = (bf16*)(ws + Q_OFF);
  bf16* k_buf  = (bf16*)(ws + K_OFF);
  bf16* v_buf  = (bf16*)(ws + V_OFF);      // v -> O
  bf16* h_buf  = (bf16*)(ws + Q_OFF);      // h spans q..v after attention path done
  float* biasT = (float*)(ws + BIAS_OFF);
  bf16* wqkv   = (bf16*)(ws + WQKV_OFF);
  bf16* wproj  = (bf16*)(ws + WPROJ_OFF);
  bf16* wglu   = (bf16*)(ws + WGLU_OFF);
  bf16* wout   = (bf16*)(ws + WOUT_OFF);

  // weight casts f32 -> bf16
  cvt_f32_bf16<<<dim3((1152 * 384 + 255) / 256), 256, 0, stream>>>(qkv_w, wqkv, 1152 * 384);
  cvt_f32_bf16<<<dim3((384 * 384 + 255) / 256), 256, 0, stream>>>(proj_w, wproj, 384 * 384);
  cvt_f32_bf16<<<dim3((2048 * 384 + 255) / 256), 256, 0, stream>>>(glu_w, wglu, 2048 * 384);
  cvt_f32_bf16<<<dim3((384 * 1024 + 255) / 256), 256, 0, stream>>>(out_w, wout, 384 * 1024);

  // rel-pos bias table (transposed)
  cpb_bias_kernel<<<1, 256, 0, stream>>>(cpb_w1, cpb_b1, cpb_w2, biasT);

  // LN1 -> bf16, windowed row order (y1 in r0)
  ln_kernel<<<TOK / 4, 256, 0, stream>>>(x, n1g, n1b, r0, 1);

  // QKV GEMM (M=184320, N=1152, K=384)
  gemm_qkv_kernel<<<dim3(9, TOK / 128), 256, 0, stream>>>(r0, wqkv, q_bias, v_bias,
                                                          q_buf, k_buf, v_buf);

  // V transpose into r0 (y1 dead)
  vtrans_kernel<<<NWIN * HEADS, 64, 0, stream>>>(v_buf, r0);

  // MFMA attention; O -> v_buf (v dead)
  attn_kernel<<<NWIN, 256, 0, stream>>>(q_buf, k_buf, r0, biasT, v_buf);

  // proj GEMM + window-reverse + x1 = x + ls1*o -> d_out (fp32)
  gemm_proj_kernel<<<dim3(3, TOK / 128), 256, 0, stream>>>(v_buf, wproj, proj_b, x, ls1, out);

  // LN2 (token-major) -> r0 as y2 (vT dead)
  ln_kernel<<<TOK / 4, 256, 0, stream>>>(out, n2g, n2b, r0, 0);

  // fused GLU GEMM -> h
  gemm_glu_kernel<<<dim3(8, TOK / 128), 256, 0, stream>>>(r0, wglu, glu_b, h_buf);

  // out GEMM, d_out += ls2*(h@W^T + b)
  gemm_out_kernel<<<dim3(3, TOK / 128), 256, 0, stream>>>(h_buf, wout, out_b, ls2, out);

  (void)in_sizes; (void)n_in; (void)out_size; (void)ws_size;
}

// Round 4
// 2620.367 us; speedup vs baseline: 1.5279x; 1.2075x over previous
//
#include <hip/hip_runtime.h>
#include <hip/hip_bf16.h>
#include <stdint.h>
#include <math.h>

using bf16 = __hip_bfloat16;
typedef __attribute__((ext_vector_type(8))) short short8;   // 8 x bf16 (4 VGPRs) — MFMA A/B frag
typedef __attribute__((ext_vector_type(4))) short short4b;  // 4 x bf16 (8B)
typedef __attribute__((ext_vector_type(4))) float f32x4;    // MFMA C/D frag

#define TOK    184320          // 16*96*120
#define CDIM   384
#define NWIN   2304            // 16*12*12
#define NTOK   80              // tokens per window
#define HEADS  12
#define BK     64

// ---------------- ws layout (bytes) ----------------
constexpr size_t R0_SZ    = (size_t)TOK * CDIM * 2;           // 141,557,760 bf16 plane
constexpr size_t R0_OFF   = 0;                                 // y1 -> vT -> y2
constexpr size_t Q_OFF    = R0_SZ;                             // q  (also start of h reuse)
constexpr size_t K_OFF    = Q_OFF + R0_SZ;
constexpr size_t V_OFF    = K_OFF + R0_SZ;                     // v -> O (attn output)
constexpr size_t BIAS_OFF = V_OFF + R0_SZ;                     // 12*6400 f32 sigmoid biasT
constexpr size_t WQKV_OFF = BIAS_OFF + (size_t)HEADS * 6400 * 4;
constexpr size_t WPROJ_OFF= WQKV_OFF + (size_t)1152 * 384 * 2;
constexpr size_t WGLU_OFF = WPROJ_OFF + (size_t)384 * 384 * 2;
constexpr size_t WOUT_OFF = WGLU_OFF + (size_t)2048 * 384 * 2;

// ---------------- helpers ----------------
__device__ __forceinline__ float b2f(unsigned short u) {
  return __uint_as_float(((unsigned)u) << 16);
}
__device__ __forceinline__ short f2bs(float x) {
  return (short)__bfloat16_as_ushort(__float2bfloat16(x));
}

__device__ __forceinline__ void gload_lds16(const void* g, void* l) {
  typedef __attribute__((address_space(1))) char gchar;
  typedef __attribute__((address_space(3))) char lchar;
  __builtin_amdgcn_global_load_lds((gchar*)(uintptr_t)g, (lchar*)(uintptr_t)l, 16, 0, 0);
}

// bijective XCD-chunked swizzle (m204): round-robin XCD id -> contiguous chunk per XCD
__device__ __forceinline__ int xcd_swz(int orig, int nwg) {
  int q = nwg >> 3, r = nwg & 7;
  int xcd = orig & 7, loc = orig >> 3;
  return (xcd < r ? xcd * (q + 1) : r * (q + 1) + (xcd - r) * q) + loc;
}

__device__ __forceinline__ int token_to_winrow(int t) {
  int b  = t / (96 * 120);
  int r  = t - b * (96 * 120);
  int hh = r / 120, ww = r - (r / 120) * 120;
  int win = b * 144 + (hh >> 3) * 12 + (ww / 10);
  int n   = (hh & 7) * 10 + (ww % 10);
  return win * NTOK + n;
}

__device__ __forceinline__ int winrow_to_token(int row) {
  int win = row / NTOK, n = row - win * NTOK;
  int b = win / 144, rem = win - b * 144;
  int hh = (rem / 12) * 8 + n / 10;
  int ww = (rem % 12) * 10 + n % 10;
  return (b * 96 + hh) * 120 + ww;
}

// ---------------- tiny kernels ----------------
__global__ void cvt_f32_bf16(const float* __restrict__ in, bf16* __restrict__ out, int n) {
  int i = blockIdx.x * 256 + threadIdx.x;
  if (i < n) out[i] = __float2bfloat16(in[i]);
}

// continuous rel-pos bias, TRANSPOSED output: biasT[h][k*80+q]
__global__ void cpb_bias_kernel(const float* __restrict__ w1, const float* __restrict__ b1,
                                const float* __restrict__ w2, float* __restrict__ biasT) {
  __shared__ float tab[285][12];
  for (int r = threadIdx.x; r < 285; r += blockDim.x) {
    int i = r / 19, j = r - (r / 19) * 19;
    float c0 = 8.0f * (float)(i - 7) / 7.0f;
    float c1 = 8.0f * (float)(j - 9) / 9.0f;
    const float inv3 = 1.0f / 3.0f;   // 1/log2(8)
    float t0 = (c0 >= 0.f ? 1.f : -1.f) * log2f(fabsf(c0) + 1.f) * inv3;
    float t1 = (c1 >= 0.f ? 1.f : -1.f) * log2f(fabsf(c1) + 1.f) * inv3;
    float acc[12];
    #pragma unroll
    for (int h = 0; h < 12; h++) acc[h] = 0.f;
    for (int k = 0; k < 512; k++) {
      float hk = fmaxf(w1[2 * k] * t0 + w1[2 * k + 1] * t1 + b1[k], 0.f);
      #pragma unroll
      for (int h = 0; h < 12; h++) acc[h] += hk * w2[h * 512 + k];
    }
    #pragma unroll
    for (int h = 0; h < 12; h++) tab[r][h] = acc[h];
  }
  __syncthreads();
  for (int e = threadIdx.x; e < 6400; e += blockDim.x) {
    int n = e / 80, m = e - (e / 80) * 80;   // n = q index, m = k index
    int id = (n / 10 - m / 10 + 7) * 19 + (n % 10 - m % 10 + 9);
    #pragma unroll
    for (int h = 0; h < 12; h++) {
      float t = tab[id][h];
      biasT[h * 6400 + m * 80 + n] = 16.0f / (1.0f + __expf(-t));
    }
  }
}

// layernorm over C=384, one wave per token; optional windowed row permutation on output
__global__ __launch_bounds__(256)
void ln_kernel(const float* __restrict__ x, const float* __restrict__ g,
               const float* __restrict__ b, bf16* __restrict__ out, int windowed) {
  const int wv = threadIdx.x >> 6, lane = threadIdx.x & 63;
  const int token = blockIdx.x * 4 + wv;
  const float* px = x + (size_t)token * CDIM;
  float v[6];
  float s = 0.f;
  #pragma unroll
  for (int j = 0; j < 6; j++) { v[j] = px[lane + 64 * j]; s += v[j]; }
  #pragma unroll
  for (int off = 32; off; off >>= 1) s += __shfl_xor(s, off);
  const float mean = s * (1.0f / 384.0f);
  float sq = 0.f;
  #pragma unroll
  for (int j = 0; j < 6; j++) { float d = v[j] - mean; sq += d * d; }
  #pragma unroll
  for (int off = 32; off; off >>= 1) sq += __shfl_xor(sq, off);
  const float rs = rsqrtf(sq * (1.0f / 384.0f) + 1e-5f);
  const int rowb = windowed ? token_to_winrow(token) : token;
  bf16* po = out + (size_t)rowb * CDIM;
  #pragma unroll
  for (int j = 0; j < 6; j++) {
    int c = lane + 64 * j;
    po[c] = __float2bfloat16((v[j] - mean) * rs * g[c] + b[c]);
  }
}

// V transpose: v[wh][80][32] -> vT[wh][32][80]
__global__ __launch_bounds__(64)
void vtrans_kernel(const bf16* __restrict__ v, bf16* __restrict__ vT) {
  __shared__ unsigned short vt[32][82];
  const int wh = blockIdx.x, t = threadIdx.x;
  const unsigned short* vg = (const unsigned short*)v + (size_t)wh * 2560;
  #pragma unroll
  for (int j = 0; j < 5; j++) {
    int c = (t + 64 * j) * 8;
    short8 u = *(const short8*)(vg + c);
    int n = c >> 5, d = c & 31;
    #pragma unroll
    for (int e = 0; e < 8; e++) vt[d + e][n] = (unsigned short)u[e];
  }
  __syncthreads();
  unsigned int* og = (unsigned int*)((unsigned short*)vT + (size_t)wh * 2560);
  #pragma unroll
  for (int j = 0; j < 20; j++) {
    int p = t + 64 * j;
    int e = p * 2;
    int d = e / 80, kcol = e - (e / 80) * 80;
    og[p] = (unsigned int)vt[d][kcol] | ((unsigned int)vt[d][kcol + 1] << 16);
  }
}

// ============ GEMM core v2: 256x128 tile, BK=64, 8 waves (4Mx2N), 2-phase dbuf ============
// Per iteration t: issue stage(t+1) loads -> ds_read+MFMA buf[t&1] -> __syncthreads()
// (the barrier's vmcnt(0) drain lands AFTER compute, so HBM latency hides under MFMA).
#define STAGE_A(buf, kt)                                                          \
  _Pragma("unroll")                                                               \
  for (int j_ = 0; j_ < 4; j_++) {                                                \
    const int ch_ = j_ * 8 + w;                                                   \
    const int el_ = ch_ * 512 + lane * 8;                                         \
    gload_lds16(Ab + (size_t)(el_ >> 6) * LDA + (kt) + (el_ & 63),                \
                As[buf] + ch_ * 512);                                             \
  }
#define STAGE_B(Bp, Bls, buf, kt)                                                 \
  _Pragma("unroll")                                                               \
  for (int j_ = 0; j_ < 2; j_++) {                                                \
    const int ch_ = j_ * 8 + w;                                                   \
    const int el_ = ch_ * 512 + lane * 8;                                         \
    gload_lds16(Bp + (size_t)(el_ >> 6) * LDA + (kt) + (el_ & 63),                \
                Bls[buf] + ch_ * 512);                                            \
  }

#define FRAG_IDX(base, m16, kk) ((base) + ((m16) + lr) * 64 + (kk) + kg * 8)

// non-fused core: acc[4][4], A 256 rows, B 128 rows
#define GEMM2_BODY(K_, NT_)                                                       \
  const int LDA = K_;                                                             \
  const int w = threadIdx.x >> 6, lane = threadIdx.x & 63;                        \
  const int wr = w >> 1, wc = w & 1, lr = lane & 15, kg = lane >> 4;              \
  f32x4 acc[4][4];                                                                \
  _Pragma("unroll")                                                               \
  for (int m = 0; m < 4; m++)                                                     \
    _Pragma("unroll")                                                             \
    for (int n = 0; n < 4; n++) acc[m][n] = (f32x4){0.f, 0.f, 0.f, 0.f};          \
  STAGE_A(0, 0) STAGE_B(Bb, Bs, 0, 0)                                             \
  __syncthreads();                                                                \
  for (int t = 0; t < NT_; t++) {                                                 \
    const int cur = t & 1;                                                        \
    if (t + 1 < NT_) { STAGE_A(cur ^ 1, (t + 1) * BK) STAGE_B(Bb, Bs, cur ^ 1, (t + 1) * BK) } \
    _Pragma("unroll")                                                             \
    for (int kk = 0; kk < BK; kk += 32) {                                         \
      short8 af[4], bfr[4];                                                       \
      _Pragma("unroll")                                                           \
      for (int m = 0; m < 4; m++)                                                 \
        af[m] = *(const short8*)FRAG_IDX(As[cur], wr * 64 + m * 16, kk);          \
      _Pragma("unroll")                                                           \
      for (int n = 0; n < 4; n++)                                                 \
        bfr[n] = *(const short8*)FRAG_IDX(Bs[cur], wc * 64 + n * 16, kk);         \
      _Pragma("unroll")                                                           \
      for (int m = 0; m < 4; m++)                                                 \
        _Pragma("unroll")                                                         \
        for (int n = 0; n < 4; n++)                                               \
          acc[m][n] = __builtin_amdgcn_mfma_f32_16x16x32_bf16(af[m], bfr[n], acc[m][n], 0, 0, 0); \
    }                                                                             \
    if (t + 1 < NT_) __syncthreads();                                             \
  }

// QKV GEMM: M=184320, N=1152, K=384; scatter epilogue to q/k/v [win][head][n][d] + bias
__global__ __launch_bounds__(512, 2)
void gemm_qkv_kernel(const bf16* __restrict__ A, const bf16* __restrict__ W,
                     const float* __restrict__ qb, const float* __restrict__ vb,
                     bf16* __restrict__ qo, bf16* __restrict__ ko, bf16* __restrict__ vo) {
  __shared__ bf16 As[2][256 * 64], Bs[2][128 * 64];
  const int nbx = 9;
  const int swz = xcd_swz(blockIdx.x, gridDim.x);
  const int by = swz / nbx, bx = swz - (swz / nbx) * nbx;
  const bf16* Ab = A + (size_t)by * 256 * 384;
  const bf16* Bb = W + (size_t)bx * 128 * 384;
  GEMM2_BODY(384, 6)
  #pragma unroll
  for (int m = 0; m < 4; m++)
    #pragma unroll
    for (int i = 0; i < 4; i++) {
      const int row = by * 256 + wr * 64 + m * 16 + kg * 4 + i;
      const int win = row / NTOK, n = row - win * NTOK;
      #pragma unroll
      for (int nn = 0; nn < 4; nn++) {
        const int col = bx * 128 + wc * 64 + nn * 16 + lr;
        const int which = col / 384;
        const int c = col - which * 384;
        const int head = c >> 5, d = c & 31;
        const size_t idx = (((size_t)win * HEADS + head) * NTOK + n) * 32 + d;
        float val = acc[m][nn][i];
        if (which == 0)      qo[idx] = __float2bfloat16(val + qb[c]);
        else if (which == 2) vo[idx] = __float2bfloat16(val + vb[c]);
        else                 ko[idx] = __float2bfloat16(val);
      }
    }
}

// proj GEMM: M=184320, N=384, K=384; reverse window perm, x1 = x + ls1*(o@W^T+b) fp32
__global__ __launch_bounds__(512, 2)
void gemm_proj_kernel(const bf16* __restrict__ A, const bf16* __restrict__ W,
                      const float* __restrict__ pb, const float* __restrict__ x,
                      const float* __restrict__ ls1, float* __restrict__ out) {
  __shared__ bf16 As[2][256 * 64], Bs[2][128 * 64];
  const int nbx = 3;
  const int swz = xcd_swz(blockIdx.x, gridDim.x);
  const int by = swz / nbx, bx = swz - (swz / nbx) * nbx;
  const bf16* Ab = A + (size_t)by * 256 * 384;
  const bf16* Bb = W + (size_t)bx * 128 * 384;
  GEMM2_BODY(384, 6)
  #pragma unroll
  for (int m = 0; m < 4; m++)
    #pragma unroll
    for (int i = 0; i < 4; i++) {
      const int row = by * 256 + wr * 64 + m * 16 + kg * 4 + i;
      const int t = winrow_to_token(row);
      #pragma unroll
      for (int nn = 0; nn < 4; nn++) {
        const int col = bx * 128 + wc * 64 + nn * 16 + lr;
        const size_t gi = (size_t)t * CDIM + col;
        out[gi] = x[gi] + ls1[col] * (acc[m][nn][i] + pb[col]);
      }
    }
}

// out GEMM: M=184320, N=384, K=1024; d_out += ls2*(h@W^T + b)
__global__ __launch_bounds__(512, 2)
void gemm_out_kernel(const bf16* __restrict__ A, const bf16* __restrict__ W,
                     const float* __restrict__ ob, const float* __restrict__ ls2,
                     float* __restrict__ out) {
  __shared__ bf16 As[2][256 * 64], Bs[2][128 * 64];
  const int nbx = 3;
  const int swz = xcd_swz(blockIdx.x, gridDim.x);
  const int by = swz / nbx, bx = swz - (swz / nbx) * nbx;
  const bf16* Ab = A + (size_t)by * 256 * 1024;
  const bf16* Bb = W + (size_t)bx * 128 * 1024;
  GEMM2_BODY(1024, 16)
  #pragma unroll
  for (int m = 0; m < 4; m++)
    #pragma unroll
    for (int i = 0; i < 4; i++) {
      const int row = by * 256 + wr * 64 + m * 16 + kg * 4 + i;
      #pragma unroll
      for (int nn = 0; nn < 4; nn++) {
        const int col = bx * 128 + wc * 64 + nn * 16 + lr;
        const size_t gi = (size_t)row * CDIM + col;
        out[gi] += ls2[col] * (acc[m][nn][i] + ob[col]);
      }
    }
}

// fused GLU GEMM: M=184320, per block 256 rows x 128 cols of each half; K=384
// h = (a+b_a) * gelu_exact(g+b_g); 128KB LDS dbuf
__global__ __launch_bounds__(512, 2)
void gemm_glu_kernel(const bf16* __restrict__ A, const bf16* __restrict__ W,
                     const float* __restrict__ gb, bf16* __restrict__ h) {
  __shared__ bf16 As[2][256 * 64], Ba[2][128 * 64], Bg[2][128 * 64];
  const int nbx = 8;
  const int swz = xcd_swz(blockIdx.x, gridDim.x);
  const int by = swz / nbx, bx = swz - (swz / nbx) * nbx;
  const bf16* Ab = A + (size_t)by * 256 * 384;
  const bf16* Wa = W + (size_t)(bx * 128) * 384;
  const bf16* Wg = W + (size_t)(1024 + bx * 128) * 384;
  const int LDA = 384;
  const int w = threadIdx.x >> 6, lane = threadIdx.x & 63;
  const int wr = w >> 1, wc = w & 1, lr = lane & 15, kg = lane >> 4;
  f32x4 aA[4][4], aG[4][4];
  #pragma unroll
  for (int m = 0; m < 4; m++)
    #pragma unroll
    for (int n = 0; n < 4; n++) {
      aA[m][n] = (f32x4){0.f, 0.f, 0.f, 0.f};
      aG[m][n] = (f32x4){0.f, 0.f, 0.f, 0.f};
    }
  STAGE_A(0, 0) STAGE_B(Wa, Ba, 0, 0) STAGE_B(Wg, Bg, 0, 0)
  __syncthreads();
  for (int t = 0; t < 6; t++) {
    const int cur = t & 1;
    if (t + 1 < 6) {
      STAGE_A(cur ^ 1, (t + 1) * BK)
      STAGE_B(Wa, Ba, cur ^ 1, (t + 1) * BK)
      STAGE_B(Wg, Bg, cur ^ 1, (t + 1) * BK)
    }
    #pragma unroll
    for (int kk = 0; kk < BK; kk += 32) {
      short8 af[4], ba[4], bg2[4];
      #pragma unroll
      for (int m = 0; m < 4; m++)
        af[m] = *(const short8*)FRAG_IDX(As[cur], wr * 64 + m * 16, kk);
      #pragma unroll
      for (int n = 0; n < 4; n++) {
        ba[n]  = *(const short8*)FRAG_IDX(Ba[cur], wc * 64 + n * 16, kk);
        bg2[n] = *(const short8*)FRAG_IDX(Bg[cur], wc * 64 + n * 16, kk);
      }
      #pragma unroll
      for (int m = 0; m < 4; m++)
        #pragma unroll
        for (int n = 0; n < 4; n++) {
          aA[m][n] = __builtin_amdgcn_mfma_f32_16x16x32_bf16(af[m], ba[n],  aA[m][n], 0, 0, 0);
          aG[m][n] = __builtin_amdgcn_mfma_f32_16x16x32_bf16(af[m], bg2[n], aG[m][n], 0, 0, 0);
        }
    }
    if (t + 1 < 6) __syncthreads();
  }
  #pragma unroll
  for (int m = 0; m < 4; m++)
    #pragma unroll
    for (int i = 0; i < 4; i++) {
      const int row = by * 256 + wr * 64 + m * 16 + kg * 4 + i;
      #pragma unroll
      for (int nn = 0; nn < 4; nn++) {
        const int col = bx * 128 + wc * 64 + nn * 16 + lr;
        float a = aA[m][nn][i] + gb[col];
        float g = aG[m][nn][i] + gb[1024 + col];
        float gelu = 0.5f * g * (1.0f + erff(g * 0.70710678118654752f));
        h[(size_t)row * 1024 + col] = __float2bfloat16(a * gelu);
      }
    }
}

// ---------------- MFMA attention: block = window, 4 waves x 3 heads, no barriers ----------------
__global__ __launch_bounds__(256, 2)
void attn_kernel(const bf16* __restrict__ q, const bf16* __restrict__ k,
                 const bf16* __restrict__ vT, const float* __restrict__ biasT,
                 bf16* __restrict__ o) {
  __shared__ short P_all[4][80 * 104];
  const int wv = threadIdx.x >> 6, lane = threadIdx.x & 63;
  const int lr = lane & 15, kg = lane >> 4;
  const int win = blockIdx.x;
  short* P = &P_all[wv][0];
  #pragma unroll
  for (int j = 0; j < 10; j++) {
    int idx = lane + 64 * j;
    int r = idx >> 3, c = idx & 7;
    *(int*)(P + r * 104 + 80 + c * 2) = 0;
  }
  for (int hh = 0; hh < 3; hh++) {
    const int head = wv * 3 + hh;
    const size_t hb = ((size_t)win * HEADS + head) * 2560;
    short8 qf[5], kf[5];
    #pragma unroll
    for (int t5 = 0; t5 < 5; t5++) {
      const int roff = (t5 * 16 + lr) * 32 + kg * 8;
      {
        short8 u = *(const short8*)((const unsigned short*)q + hb + roff);
        float f[8]; float s = 0.f;
        #pragma unroll
        for (int j2 = 0; j2 < 8; j2++) { float x = b2f((unsigned short)u[j2]); f[j2] = x; s += x * x; }
        s += __shfl_xor(s, 16); s += __shfl_xor(s, 32);
        float sc = 1.0f / (sqrtf(s) + 5e-5f);
        short8 r8;
        #pragma unroll
        for (int j2 = 0; j2 < 8; j2++) r8[j2] = f2bs(f[j2] * sc);
        qf[t5] = r8;
      }
      {
        short8 u = *(const short8*)((const unsigned short*)k + hb + roff);
        float f[8]; float s = 0.f;
        #pragma unroll
        for (int j2 = 0; j2 < 8; j2++) { float x = b2f((unsigned short)u[j2]); f[j2] = x; s += x * x; }
        s += __shfl_xor(s, 16); s += __shfl_xor(s, 32);
        float sc = 1.0f / (sqrtf(s) + 5e-5f);
        short8 r8;
        #pragma unroll
        for (int j2 = 0; j2 < 8; j2++) r8[j2] = f2bs(f[j2] * sc);
        kf[t5] = r8;
      }
    }
    f32x4 st[5][5];
    #pragma unroll
    for (int a = 0; a < 5; a++)
      #pragma unroll
      for (int b = 0; b < 5; b++) st[a][b] = (f32x4){0.f, 0.f, 0.f, 0.f};
    #pragma unroll
    for (int a = 0; a < 5; a++)
      #pragma unroll
      for (int b = 0; b < 5; b++)
        st[a][b] = __builtin_amdgcn_mfma_f32_16x16x32_bf16(kf[a], qf[b], st[a][b], 0, 0, 0);
    const float* bh = biasT + head * 6400;
    #pragma unroll
    for (int a = 0; a < 5; a++)
      #pragma unroll
      for (int b = 0; b < 5; b++)
        #pragma unroll
        for (int i = 0; i < 4; i++)
          st[a][b][i] += bh[(a * 16 + kg * 4 + i) * 80 + b * 16 + lr];
    float inv[5];
    #pragma unroll
    for (int b = 0; b < 5; b++) {
      float mx = -1e30f;
      #pragma unroll
      for (int a = 0; a < 5; a++)
        #pragma unroll
        for (int i = 0; i < 4; i++) mx = fmaxf(mx, st[a][b][i]);
      mx = fmaxf(mx, __shfl_xor(mx, 16));
      mx = fmaxf(mx, __shfl_xor(mx, 32));
      float sm = 0.f;
      #pragma unroll
      for (int a = 0; a < 5; a++)
        #pragma unroll
        for (int i = 0; i < 4; i++) { float e = __expf(st[a][b][i] - mx); st[a][b][i] = e; sm += e; }
      sm += __shfl_xor(sm, 16); sm += __shfl_xor(sm, 32);
      inv[b] = 1.0f / sm;
    }
    #pragma unroll
    for (int a = 0; a < 5; a++)
      #pragma unroll
      for (int b = 0; b < 5; b++) {
        short4b pk;
        #pragma unroll
        for (int i = 0; i < 4; i++) pk[i] = f2bs(st[a][b][i] * inv[b]);
        *(short4b*)(P + (b * 16 + lr) * 104 + a * 16 + kg * 4) = pk;
      }
    const unsigned short* vh = (const unsigned short*)vT + hb;   // [32][80]
    short8 vf[2][3];
    #pragma unroll
    for (int dt = 0; dt < 2; dt++)
      #pragma unroll
      for (int ks = 0; ks < 3; ks++) {
        const int kb = ks * 32 + ((ks == 2 && kg >= 2) ? 0 : kg * 8);
        vf[dt][ks] = *(const short8*)(vh + (dt * 16 + lr) * 80 + kb);
      }
    f32x4 oc[5][2];
    #pragma unroll
    for (int b = 0; b < 5; b++)
      #pragma unroll
      for (int dt = 0; dt < 2; dt++) oc[b][dt] = (f32x4){0.f, 0.f, 0.f, 0.f};
    #pragma unroll
    for (int b = 0; b < 5; b++) {
      short8 pa[3];
      #pragma unroll
      for (int ks = 0; ks < 3; ks++)
        pa[ks] = *(const short8*)(P + (b * 16 + lr) * 104 + ks * 32 + kg * 8);
      #pragma unroll
      for (int dt = 0; dt < 2; dt++)
        #pragma unroll
        for (int ks = 0; ks < 3; ks++)
          oc[b][dt] = __builtin_amdgcn_mfma_f32_16x16x32_bf16(pa[ks], vf[dt][ks], oc[b][dt], 0, 0, 0);
    }
    unsigned short* ob = (unsigned short*)o + (size_t)win * NTOK * CDIM + head * 32;
    #pragma unroll
    for (int b = 0; b < 5; b++)
      #pragma unroll
      for (int i = 0; i < 4; i++) {
        const int row = b * 16 + kg * 4 + i;
        #pragma unroll
        for (int dt = 0; dt < 2; dt++)
          ob[(size_t)row * CDIM + dt * 16 + lr] = (unsigned short)f2bs(oc[b][dt][i]);
      }
  }
}

// ---------------- launcher ----------------
extern "C" void kernel_launch(void* const* d_in, const int* in_sizes, int n_in,
                              void* d_out, int out_size, void* d_ws, size_t ws_size,
                              hipStream_t stream) {
  const float* x       = (const float*)d_in[0];
  const float* n1g     = (const float*)d_in[1];
  const float* n1b     = (const float*)d_in[2];
  const float* qkv_w   = (const float*)d_in[3];
  const float* q_bias  = (const float*)d_in[4];
  const float* v_bias  = (const float*)d_in[5];
  const float* cpb_w1  = (const float*)d_in[6];
  const float* cpb_b1  = (const float*)d_in[7];
  const float* cpb_w2  = (const float*)d_in[8];
  const float* proj_w  = (const float*)d_in[9];
  const float* proj_b  = (const float*)d_in[10];
  const float* ls1     = (const float*)d_in[11];
  const float* n2g     = (const float*)d_in[12];
  const float* n2b     = (const float*)d_in[13];
  const float* glu_w   = (const float*)d_in[14];
  const float* glu_b   = (const float*)d_in[15];
  const float* out_w   = (const float*)d_in[16];
  const float* out_b   = (const float*)d_in[17];
  const float* ls2     = (const float*)d_in[18];
  float* out = (float*)d_out;

  char* ws = (char*)d_ws;
  bf16* r0     = (bf16*)(ws + R0_OFF);     // y1 -> vT -> y2
  bf16* q_buf  = (bf16*)(ws + Q_OFF);
  bf16* k_buf  = (bf16*)(ws + K_OFF);
  bf16* v_buf  = (bf16*)(ws + V_OFF);      // v -> O
  bf16* h_buf  = (bf16*)(ws + Q_OFF);      // h spans q..v after attention path done
  float* biasT = (float*)(ws + BIAS_OFF);
  bf16* wqkv   = (bf16*)(ws + WQKV_OFF);
  bf16* wproj  = (bf16*)(ws + WPROJ_OFF);
  bf16* wglu   = (bf16*)(ws + WGLU_OFF);
  bf16* wout   = (bf16*)(ws + WOUT_OFF);

  // weight casts f32 -> bf16
  cvt_f32_bf16<<<dim3((1152 * 384 + 255) / 256), 256, 0, stream>>>(qkv_w, wqkv, 1152 * 384);
  cvt_f32_bf16<<<dim3((384 * 384 + 255) / 256), 256, 0, stream>>>(proj_w, wproj, 384 * 384);
  cvt_f32_bf16<<<dim3((2048 * 384 + 255) / 256), 256, 0, stream>>>(glu_w, wglu, 2048 * 384);
  cvt_f32_bf16<<<dim3((384 * 1024 + 255) / 256), 256, 0, stream>>>(out_w, wout, 384 * 1024);

  // rel-pos bias table (transposed)
  cpb_bias_kernel<<<1, 256, 0, stream>>>(cpb_w1, cpb_b1, cpb_w2, biasT);

  // LN1 -> bf16, windowed row order (y1 in r0)
  ln_kernel<<<TOK / 4, 256, 0, stream>>>(x, n1g, n1b, r0, 1);

  // QKV GEMM (M=184320, N=1152, K=384): 720 x 9 tiles
  gemm_qkv_kernel<<<720 * 9, 512, 0, stream>>>(r0, wqkv, q_bias, v_bias, q_buf, k_buf, v_buf);

  // V transpose into r0 (y1 dead)
  vtrans_kernel<<<NWIN * HEADS, 64, 0, stream>>>(v_buf, r0);

  // MFMA attention; O -> v_buf (v dead)
  attn_kernel<<<NWIN, 256, 0, stream>>>(q_buf, k_buf, r0, biasT, v_buf);

  // proj GEMM + window-reverse + x1 = x + ls1*o -> d_out (fp32): 720 x 3 tiles
  gemm_proj_kernel<<<720 * 3, 512, 0, stream>>>(v_buf, wproj, proj_b, x, ls1, out);

  // LN2 (token-major) -> r0 as y2 (vT dead)
  ln_kernel<<<TOK / 4, 256, 0, stream>>>(out, n2g, n2b, r0, 0);

  // fused GLU GEMM -> h: 720 x 8 tiles
  gemm_glu_kernel<<<720 * 8, 512, 0, stream>>>(r0, wglu, glu_b, h_buf);

  // out GEMM (K=1024), d_out += ls2*(h@W^T + b): 720 x 3 tiles
  gemm_out_kernel<<<720 * 3, 512, 0, stream>>>(h_buf, wout, out_b, ls2, out);

  (void)in_sizes; (void)n_in; (void)out_size; (void)ws_size;
}

// Round 5
// 2515.046 us; speedup vs baseline: 1.5919x; 1.0419x over previous
//
#include <hip/hip_runtime.h>
#include <hip/hip_bf16.h>
#include <stdint.h>
#include <math.h>

using bf16 = __hip_bfloat16;
typedef __attribute__((ext_vector_type(8))) short short8;   // 8 x bf16 (4 VGPRs) — MFMA A/B frag
typedef __attribute__((ext_vector_type(4))) short short4b;  // 4 x bf16 (8B)
typedef __attribute__((ext_vector_type(4))) float f32x4;    // MFMA C/D frag

#define TOK    184320          // 16*96*120
#define CDIM   384
#define NWIN   2304            // 16*12*12
#define NTOK   80              // tokens per window
#define HEADS  12
#define BK     64

// ---------------- ws layout (bytes) ----------------
constexpr size_t R0_SZ    = (size_t)TOK * CDIM * 2;           // 141,557,760 bf16 plane
constexpr size_t R0_OFF   = 0;                                 // y1 -> vT -> y2
constexpr size_t Q_OFF    = R0_SZ;                             // q  (also start of h reuse)
constexpr size_t K_OFF    = Q_OFF + R0_SZ;
constexpr size_t V_OFF    = K_OFF + R0_SZ;                     // v -> O (attn output)
constexpr size_t BIAS_OFF = V_OFF + R0_SZ;                     // 12*6400 f32 sigmoid biasT
constexpr size_t WQKV_OFF = BIAS_OFF + (size_t)HEADS * 6400 * 4;
constexpr size_t WPROJ_OFF= WQKV_OFF + (size_t)1152 * 384 * 2;
constexpr size_t WGLU_OFF = WPROJ_OFF + (size_t)384 * 384 * 2;
constexpr size_t WOUT_OFF = WGLU_OFF + (size_t)2048 * 384 * 2;

// ---------------- helpers ----------------
__device__ __forceinline__ float b2f(unsigned short u) {
  return __uint_as_float(((unsigned)u) << 16);
}
__device__ __forceinline__ short f2bs(float x) {
  return (short)__bfloat16_as_ushort(__float2bfloat16(x));
}

__device__ __forceinline__ void gload_lds16(const void* g, void* l) {
  typedef __attribute__((address_space(1))) char gchar;
  typedef __attribute__((address_space(3))) char lchar;
  __builtin_amdgcn_global_load_lds((gchar*)(uintptr_t)g, (lchar*)(uintptr_t)l, 16, 0, 0);
}

// bijective XCD-chunked swizzle (m204)
__device__ __forceinline__ int xcd_swz(int orig, int nwg) {
  int q = nwg >> 3, r = nwg & 7;
  int xcd = orig & 7, loc = orig >> 3;
  return (xcd < r ? xcd * (q + 1) : r * (q + 1) + (xcd - r) * q) + loc;
}

__device__ __forceinline__ int token_to_winrow(int t) {
  int b  = t / (96 * 120);
  int r  = t - b * (96 * 120);
  int hh = r / 120, ww = r - (r / 120) * 120;
  int win = b * 144 + (hh >> 3) * 12 + (ww / 10);
  int n   = (hh & 7) * 10 + (ww % 10);
  return win * NTOK + n;
}

__device__ __forceinline__ int winrow_to_token(int row) {
  int win = row / NTOK, n = row - win * NTOK;
  int b = win / 144, rem = win - b * 144;
  int hh = (rem / 12) * 8 + n / 10;
  int ww = (rem % 12) * 10 + n % 10;
  return (b * 96 + hh) * 120 + ww;
}

// T2 swizzle: bf16-element column XOR within a 64-col (128B) row; involution.
#define SWZ_COL(c_, r_) ((c_) ^ (((r_) & 7) << 3))

// ---------------- tiny kernels ----------------
__global__ void cvt_f32_bf16(const float* __restrict__ in, bf16* __restrict__ out, int n) {
  int i = blockIdx.x * 256 + threadIdx.x;
  if (i < n) out[i] = __float2bfloat16(in[i]);
}

// continuous rel-pos bias, TRANSPOSED output: biasT[h][k*80+q]
__global__ void cpb_bias_kernel(const float* __restrict__ w1, const float* __restrict__ b1,
                                const float* __restrict__ w2, float* __restrict__ biasT) {
  __shared__ float tab[285][12];
  for (int r = threadIdx.x; r < 285; r += blockDim.x) {
    int i = r / 19, j = r - (r / 19) * 19;
    float c0 = 8.0f * (float)(i - 7) / 7.0f;
    float c1 = 8.0f * (float)(j - 9) / 9.0f;
    const float inv3 = 1.0f / 3.0f;   // 1/log2(8)
    float t0 = (c0 >= 0.f ? 1.f : -1.f) * log2f(fabsf(c0) + 1.f) * inv3;
    float t1 = (c1 >= 0.f ? 1.f : -1.f) * log2f(fabsf(c1) + 1.f) * inv3;
    float acc[12];
    #pragma unroll
    for (int h = 0; h < 12; h++) acc[h] = 0.f;
    for (int k = 0; k < 512; k++) {
      float hk = fmaxf(w1[2 * k] * t0 + w1[2 * k + 1] * t1 + b1[k], 0.f);
      #pragma unroll
      for (int h = 0; h < 12; h++) acc[h] += hk * w2[h * 512 + k];
    }
    #pragma unroll
    for (int h = 0; h < 12; h++) tab[r][h] = acc[h];
  }
  __syncthreads();
  for (int e = threadIdx.x; e < 6400; e += blockDim.x) {
    int n = e / 80, m = e - (e / 80) * 80;   // n = q index, m = k index
    int id = (n / 10 - m / 10 + 7) * 19 + (n % 10 - m % 10 + 9);
    #pragma unroll
    for (int h = 0; h < 12; h++) {
      float t = tab[id][h];
      biasT[h * 6400 + m * 80 + n] = 16.0f / (1.0f + __expf(-t));
    }
  }
}

// layernorm over C=384, one wave per token; optional windowed row permutation on output
__global__ __launch_bounds__(256)
void ln_kernel(const float* __restrict__ x, const float* __restrict__ g,
               const float* __restrict__ b, bf16* __restrict__ out, int windowed) {
  const int wv = threadIdx.x >> 6, lane = threadIdx.x & 63;
  const int token = blockIdx.x * 4 + wv;
  const float* px = x + (size_t)token * CDIM;
  float v[6];
  float s = 0.f;
  #pragma unroll
  for (int j = 0; j < 6; j++) { v[j] = px[lane + 64 * j]; s += v[j]; }
  #pragma unroll
  for (int off = 32; off; off >>= 1) s += __shfl_xor(s, off);
  const float mean = s * (1.0f / 384.0f);
  float sq = 0.f;
  #pragma unroll
  for (int j = 0; j < 6; j++) { float d = v[j] - mean; sq += d * d; }
  #pragma unroll
  for (int off = 32; off; off >>= 1) sq += __shfl_xor(sq, off);
  const float rs = rsqrtf(sq * (1.0f / 384.0f) + 1e-5f);
  const int rowb = windowed ? token_to_winrow(token) : token;
  bf16* po = out + (size_t)rowb * CDIM;
  #pragma unroll
  for (int j = 0; j < 6; j++) {
    int c = lane + 64 * j;
    po[c] = __float2bfloat16((v[j] - mean) * rs * g[c] + b[c]);
  }
}

// V transpose: v[wh][80][32] -> vT[wh][32][80]
__global__ __launch_bounds__(64)
void vtrans_kernel(const bf16* __restrict__ v, bf16* __restrict__ vT) {
  __shared__ unsigned short vt[32][82];
  const int wh = blockIdx.x, t = threadIdx.x;
  const unsigned short* vg = (const unsigned short*)v + (size_t)wh * 2560;
  #pragma unroll
  for (int j = 0; j < 5; j++) {
    int c = (t + 64 * j) * 8;
    short8 u = *(const short8*)(vg + c);
    int n = c >> 5, d = c & 31;
    #pragma unroll
    for (int e = 0; e < 8; e++) vt[d + e][n] = (unsigned short)u[e];
  }
  __syncthreads();
  unsigned int* og = (unsigned int*)((unsigned short*)vT + (size_t)wh * 2560);
  #pragma unroll
  for (int j = 0; j < 20; j++) {
    int p = t + 64 * j;
    int e = p * 2;
    int d = e / 80, kcol = e - (e / 80) * 80;
    og[p] = (unsigned int)vt[d][kcol] | ((unsigned int)vt[d][kcol + 1] << 16);
  }
}

// ======== GEMM core v3: 256x128 tile, BK=64, 8 waves, 3-buffer depth-2, counted vmcnt ========
// Per K-step: {vmcnt(6) [own loads(t) landed] -> s_barrier [publish; frees buf (t-1)%3]
//              -> stage(t+2) [6 gload_lds, stay in flight 2 phases] -> ds_read+MFMA buf[t%3]}.
// T2: LDS dest linear; global SOURCE col pre-XOR'd; ds_read col XOR'd (same involution).
#define STAGE3_A(buf, kt)                                                         \
  _Pragma("unroll")                                                               \
  for (int j_ = 0; j_ < 4; j_++) {                                                \
    const int ch_ = j_ * 8 + w;                                                   \
    const int el_ = ch_ * 512 + lane * 8;                                         \
    const int r_ = el_ >> 6, c_ = el_ & 63;                                       \
    gload_lds16(Ab + (size_t)r_ * LDA + (kt) + SWZ_COL(c_, r_),                   \
                As3 + (buf) * (256 * 64) + ch_ * 512);                            \
  }
#define STAGE3_B(Bp, Bls, nb_, buf, kt)                                           \
  _Pragma("unroll")                                                               \
  for (int j_ = 0; j_ < (nb_); j_++) {                                            \
    const int ch_ = j_ * 8 + w;                                                   \
    const int el_ = ch_ * 512 + lane * 8;                                         \
    const int r_ = el_ >> 6, c_ = el_ & 63;                                       \
    gload_lds16(Bp + (size_t)r_ * LDA + (kt) + SWZ_COL(c_, r_),                   \
                Bls + (buf) * (128 * 64) + ch_ * 512);                            \
  }

#define COMPUTE3(buf)                                                             \
  {                                                                               \
    const bf16* A_ = As3 + (buf) * (256 * 64);                                    \
    const bf16* B_ = Bs3 + (buf) * (128 * 64);                                    \
    _Pragma("unroll")                                                             \
    for (int kk = 0; kk < BK; kk += 32) {                                         \
      const int cs_ = SWZ_COL(kk + kg * 8, lr);                                   \
      short8 af[4], bfr[4];                                                       \
      _Pragma("unroll")                                                           \
      for (int m = 0; m < 4; m++)                                                 \
        af[m] = *(const short8*)(A_ + (wr * 64 + m * 16 + lr) * 64 + cs_);        \
      _Pragma("unroll")                                                           \
      for (int n = 0; n < 4; n++)                                                 \
        bfr[n] = *(const short8*)(B_ + (wc * 64 + n * 16 + lr) * 64 + cs_);       \
      __builtin_amdgcn_s_setprio(1);                                              \
      _Pragma("unroll")                                                           \
      for (int m = 0; m < 4; m++)                                                 \
        _Pragma("unroll")                                                         \
        for (int n = 0; n < 4; n++)                                               \
          acc[m][n] = __builtin_amdgcn_mfma_f32_16x16x32_bf16(af[m], bfr[n], acc[m][n], 0, 0, 0); \
      __builtin_amdgcn_s_setprio(0);                                              \
    }                                                                             \
  }

#define GEMM3_BODY(K_, NT_)                                                       \
  const int LDA = K_;                                                             \
  const int w = threadIdx.x >> 6, lane = threadIdx.x & 63;                        \
  const int wr = w >> 1, wc = w & 1, lr = lane & 15, kg = lane >> 4;              \
  f32x4 acc[4][4];                                                                \
  _Pragma("unroll")                                                               \
  for (int m = 0; m < 4; m++)                                                     \
    _Pragma("unroll")                                                             \
    for (int n = 0; n < 4; n++) acc[m][n] = (f32x4){0.f, 0.f, 0.f, 0.f};          \
  STAGE3_A(0, 0) STAGE3_B(Bb, Bs3, 2, 0, 0)                                       \
  STAGE3_A(1, BK) STAGE3_B(Bb, Bs3, 2, 1, BK)                                     \
  _Pragma("unroll")                                                               \
  for (int t = 0; t < NT_ - 1; t++) {                                             \
    asm volatile("s_waitcnt vmcnt(6)" ::: "memory");                              \
    __builtin_amdgcn_s_barrier();                                                 \
    if (t + 2 < NT_) {                                                            \
      STAGE3_A((t + 2) % 3, (t + 2) * BK)                                         \
      STAGE3_B(Bb, Bs3, 2, (t + 2) % 3, (t + 2) * BK)                             \
    }                                                                             \
    COMPUTE3(t % 3)                                                               \
  }                                                                               \
  asm volatile("s_waitcnt vmcnt(0)" ::: "memory");                                \
  __builtin_amdgcn_s_barrier();                                                   \
  COMPUTE3((NT_ - 1) % 3)

// QKV GEMM: M=184320, N=1152, K=384; scatter epilogue to q/k/v [win][head][n][d] + bias
__global__ __launch_bounds__(512, 2)
void gemm_qkv_kernel(const bf16* __restrict__ A, const bf16* __restrict__ W,
                     const float* __restrict__ qb, const float* __restrict__ vb,
                     bf16* __restrict__ qo, bf16* __restrict__ ko, bf16* __restrict__ vo) {
  __shared__ __align__(16) bf16 As3[3 * 256 * 64];
  __shared__ __align__(16) bf16 Bs3[3 * 128 * 64];
  const int nbx = 9;
  const int swz = xcd_swz(blockIdx.x, gridDim.x);
  const int by = swz / nbx, bx = swz - (swz / nbx) * nbx;
  const bf16* Ab = A + (size_t)by * 256 * 384;
  const bf16* Bb = W + (size_t)bx * 128 * 384;
  GEMM3_BODY(384, 6)
  #pragma unroll
  for (int m = 0; m < 4; m++)
    #pragma unroll
    for (int i = 0; i < 4; i++) {
      const int row = by * 256 + wr * 64 + m * 16 + kg * 4 + i;
      const int win = row / NTOK, n = row - win * NTOK;
      #pragma unroll
      for (int nn = 0; nn < 4; nn++) {
        const int col = bx * 128 + wc * 64 + nn * 16 + lr;
        const int which = col / 384;
        const int c = col - which * 384;
        const int head = c >> 5, d = c & 31;
        const size_t idx = (((size_t)win * HEADS + head) * NTOK + n) * 32 + d;
        float val = acc[m][nn][i];
        if (which == 0)      qo[idx] = __float2bfloat16(val + qb[c]);
        else if (which == 2) vo[idx] = __float2bfloat16(val + vb[c]);
        else                 ko[idx] = __float2bfloat16(val);
      }
    }
}

// proj GEMM: M=184320, N=384, K=384; reverse window perm, x1 = x + ls1*(o@W^T+b) fp32
__global__ __launch_bounds__(512, 2)
void gemm_proj_kernel(const bf16* __restrict__ A, const bf16* __restrict__ W,
                      const float* __restrict__ pb, const float* __restrict__ x,
                      const float* __restrict__ ls1, float* __restrict__ out) {
  __shared__ __align__(16) bf16 As3[3 * 256 * 64];
  __shared__ __align__(16) bf16 Bs3[3 * 128 * 64];
  const int nbx = 3;
  const int swz = xcd_swz(blockIdx.x, gridDim.x);
  const int by = swz / nbx, bx = swz - (swz / nbx) * nbx;
  const bf16* Ab = A + (size_t)by * 256 * 384;
  const bf16* Bb = W + (size_t)bx * 128 * 384;
  GEMM3_BODY(384, 6)
  #pragma unroll
  for (int m = 0; m < 4; m++)
    #pragma unroll
    for (int i = 0; i < 4; i++) {
      const int row = by * 256 + wr * 64 + m * 16 + kg * 4 + i;
      const int t = winrow_to_token(row);
      #pragma unroll
      for (int nn = 0; nn < 4; nn++) {
        const int col = bx * 128 + wc * 64 + nn * 16 + lr;
        const size_t gi = (size_t)t * CDIM + col;
        out[gi] = x[gi] + ls1[col] * (acc[m][nn][i] + pb[col]);
      }
    }
}

// out GEMM: M=184320, N=384, K=1024; d_out += ls2*(h@W^T + b)
__global__ __launch_bounds__(512, 2)
void gemm_out_kernel(const bf16* __restrict__ A, const bf16* __restrict__ W,
                     const float* __restrict__ ob, const float* __restrict__ ls2,
                     float* __restrict__ out) {
  __shared__ __align__(16) bf16 As3[3 * 256 * 64];
  __shared__ __align__(16) bf16 Bs3[3 * 128 * 64];
  const int nbx = 3;
  const int swz = xcd_swz(blockIdx.x, gridDim.x);
  const int by = swz / nbx, bx = swz - (swz / nbx) * nbx;
  const bf16* Ab = A + (size_t)by * 256 * 1024;
  const bf16* Bb = W + (size_t)bx * 128 * 1024;
  GEMM3_BODY(1024, 16)
  #pragma unroll
  for (int m = 0; m < 4; m++)
    #pragma unroll
    for (int i = 0; i < 4; i++) {
      const int row = by * 256 + wr * 64 + m * 16 + kg * 4 + i;
      #pragma unroll
      for (int nn = 0; nn < 4; nn++) {
        const int col = bx * 128 + wc * 64 + nn * 16 + lr;
        const size_t gi = (size_t)row * CDIM + col;
        out[gi] += ls2[col] * (acc[m][nn][i] + ob[col]);
      }
    }
}

// fused GLU GEMM: BM=128, 128 cols of EACH half per block; K=384; 3-buffer depth-2.
// 8 waves as 4M x 2N: per-wave 32 rows x 64 cols; acc[2][4] per half.
__global__ __launch_bounds__(512, 2)
void gemm_glu_kernel(const bf16* __restrict__ A, const bf16* __restrict__ W,
                     const float* __restrict__ gb, bf16* __restrict__ h) {
  __shared__ __align__(16) bf16 Asl[3 * 128 * 64];
  __shared__ __align__(16) bf16 Bal[3 * 128 * 64];
  __shared__ __align__(16) bf16 Bgl[3 * 128 * 64];
  const int nbx = 8;
  const int swz = xcd_swz(blockIdx.x, gridDim.x);
  const int by = swz / nbx, bx = swz - (swz / nbx) * nbx;
  const bf16* Ab = A + (size_t)by * 128 * 384;
  const bf16* Wa = W + (size_t)(bx * 128) * 384;
  const bf16* Wg = W + (size_t)(1024 + bx * 128) * 384;
  const int LDA = 384;
  const int w = threadIdx.x >> 6, lane = threadIdx.x & 63;
  const int wr = w >> 1, wc = w & 1, lr = lane & 15, kg = lane >> 4;
  f32x4 aA[2][4], aG[2][4];
  #pragma unroll
  for (int m = 0; m < 2; m++)
    #pragma unroll
    for (int n = 0; n < 4; n++) {
      aA[m][n] = (f32x4){0.f, 0.f, 0.f, 0.f};
      aG[m][n] = (f32x4){0.f, 0.f, 0.f, 0.f};
    }
  STAGE3_B(Ab, Asl, 2, 0, 0) STAGE3_B(Wa, Bal, 2, 0, 0) STAGE3_B(Wg, Bgl, 2, 0, 0)
  STAGE3_B(Ab, Asl, 2, 1, BK) STAGE3_B(Wa, Bal, 2, 1, BK) STAGE3_B(Wg, Bgl, 2, 1, BK)
  #pragma unroll
  for (int t = 0; t < 5; t++) {
    asm volatile("s_waitcnt vmcnt(6)" ::: "memory");
    __builtin_amdgcn_s_barrier();
    if (t + 2 < 6) {
      STAGE3_B(Ab, Asl, 2, (t + 2) % 3, (t + 2) * BK)
      STAGE3_B(Wa, Bal, 2, (t + 2) % 3, (t + 2) * BK)
      STAGE3_B(Wg, Bgl, 2, (t + 2) % 3, (t + 2) * BK)
    }
    {
      const bf16* A_ = Asl + (t % 3) * (128 * 64);
      const bf16* Ba_ = Bal + (t % 3) * (128 * 64);
      const bf16* Bg_ = Bgl + (t % 3) * (128 * 64);
      #pragma unroll
      for (int kk = 0; kk < BK; kk += 32) {
        const int cs_ = SWZ_COL(kk + kg * 8, lr);
        short8 af[2], ba[4], bg2[4];
        #pragma unroll
        for (int m = 0; m < 2; m++)
          af[m] = *(const short8*)(A_ + (wr * 32 + m * 16 + lr) * 64 + cs_);
        #pragma unroll
        for (int n = 0; n < 4; n++) {
          ba[n]  = *(const short8*)(Ba_ + (wc * 64 + n * 16 + lr) * 64 + cs_);
          bg2[n] = *(const short8*)(Bg_ + (wc * 64 + n * 16 + lr) * 64 + cs_);
        }
        __builtin_amdgcn_s_setprio(1);
        #pragma unroll
        for (int m = 0; m < 2; m++)
          #pragma unroll
          for (int n = 0; n < 4; n++) {
            aA[m][n] = __builtin_amdgcn_mfma_f32_16x16x32_bf16(af[m], ba[n],  aA[m][n], 0, 0, 0);
            aG[m][n] = __builtin_amdgcn_mfma_f32_16x16x32_bf16(af[m], bg2[n], aG[m][n], 0, 0, 0);
          }
        __builtin_amdgcn_s_setprio(0);
      }
    }
  }
  asm volatile("s_waitcnt vmcnt(0)" ::: "memory");
  __builtin_amdgcn_s_barrier();
  {
    const bf16* A_ = Asl + (5 % 3) * (128 * 64);
    const bf16* Ba_ = Bal + (5 % 3) * (128 * 64);
    const bf16* Bg_ = Bgl + (5 % 3) * (128 * 64);
    #pragma unroll
    for (int kk = 0; kk < BK; kk += 32) {
      const int cs_ = SWZ_COL(kk + kg * 8, lr);
      short8 af[2], ba[4], bg2[4];
      #pragma unroll
      for (int m = 0; m < 2; m++)
        af[m] = *(const short8*)(A_ + (wr * 32 + m * 16 + lr) * 64 + cs_);
      #pragma unroll
      for (int n = 0; n < 4; n++) {
        ba[n]  = *(const short8*)(Ba_ + (wc * 64 + n * 16 + lr) * 64 + cs_);
        bg2[n] = *(const short8*)(Bg_ + (wc * 64 + n * 16 + lr) * 64 + cs_);
      }
      __builtin_amdgcn_s_setprio(1);
      #pragma unroll
      for (int m = 0; m < 2; m++)
        #pragma unroll
        for (int n = 0; n < 4; n++) {
          aA[m][n] = __builtin_amdgcn_mfma_f32_16x16x32_bf16(af[m], ba[n],  aA[m][n], 0, 0, 0);
          aG[m][n] = __builtin_amdgcn_mfma_f32_16x16x32_bf16(af[m], bg2[n], aG[m][n], 0, 0, 0);
        }
      __builtin_amdgcn_s_setprio(0);
    }
  }
  #pragma unroll
  for (int m = 0; m < 2; m++)
    #pragma unroll
    for (int i = 0; i < 4; i++) {
      const int row = by * 128 + wr * 32 + m * 16 + kg * 4 + i;
      #pragma unroll
      for (int nn = 0; nn < 4; nn++) {
        const int col = bx * 128 + wc * 64 + nn * 16 + lr;
        float a = aA[m][nn][i] + gb[col];
        float g = aG[m][nn][i] + gb[1024 + col];
        float gelu = 0.5f * g * (1.0f + erff(g * 0.70710678118654752f));
        h[(size_t)row * 1024 + col] = __float2bfloat16(a * gelu);
      }
    }
}

// ---------------- MFMA attention: block = window, 4 waves x 3 heads, no barriers ----------------
__global__ __launch_bounds__(256, 2)
void attn_kernel(const bf16* __restrict__ q, const bf16* __restrict__ k,
                 const bf16* __restrict__ vT, const float* __restrict__ biasT,
                 bf16* __restrict__ o) {
  __shared__ short P_all[4][80 * 104];
  const int wv = threadIdx.x >> 6, lane = threadIdx.x & 63;
  const int lr = lane & 15, kg = lane >> 4;
  const int win = blockIdx.x;
  short* P = &P_all[wv][0];
  #pragma unroll
  for (int j = 0; j < 10; j++) {
    int idx = lane + 64 * j;
    int r = idx >> 3, c = idx & 7;
    *(int*)(P + r * 104 + 80 + c * 2) = 0;
  }
  for (int hh = 0; hh < 3; hh++) {
    const int head = wv * 3 + hh;
    const size_t hb = ((size_t)win * HEADS + head) * 2560;
    short8 qf[5], kf[5];
    #pragma unroll
    for (int t5 = 0; t5 < 5; t5++) {
      const int roff = (t5 * 16 + lr) * 32 + kg * 8;
      {
        short8 u = *(const short8*)((const unsigned short*)q + hb + roff);
        float f[8]; float s = 0.f;
        #pragma unroll
        for (int j2 = 0; j2 < 8; j2++) { float x = b2f((unsigned short)u[j2]); f[j2] = x; s += x * x; }
        s += __shfl_xor(s, 16); s += __shfl_xor(s, 32);
        float sc = 1.0f / (sqrtf(s) + 5e-5f);
        short8 r8;
        #pragma unroll
        for (int j2 = 0; j2 < 8; j2++) r8[j2] = f2bs(f[j2] * sc);
        qf[t5] = r8;
      }
      {
        short8 u = *(const short8*)((const unsigned short*)k + hb + roff);
        float f[8]; float s = 0.f;
        #pragma unroll
        for (int j2 = 0; j2 < 8; j2++) { float x = b2f((unsigned short)u[j2]); f[j2] = x; s += x * x; }
        s += __shfl_xor(s, 16); s += __shfl_xor(s, 32);
        float sc = 1.0f / (sqrtf(s) + 5e-5f);
        short8 r8;
        #pragma unroll
        for (int j2 = 0; j2 < 8; j2++) r8[j2] = f2bs(f[j2] * sc);
        kf[t5] = r8;
      }
    }
    f32x4 st[5][5];
    #pragma unroll
    for (int a = 0; a < 5; a++)
      #pragma unroll
      for (int b = 0; b < 5; b++) st[a][b] = (f32x4){0.f, 0.f, 0.f, 0.f};
    #pragma unroll
    for (int a = 0; a < 5; a++)
      #pragma unroll
      for (int b = 0; b < 5; b++)
        st[a][b] = __builtin_amdgcn_mfma_f32_16x16x32_bf16(kf[a], qf[b], st[a][b], 0, 0, 0);
    const float* bh = biasT + head * 6400;
    #pragma unroll
    for (int a = 0; a < 5; a++)
      #pragma unroll
      for (int b = 0; b < 5; b++)
        #pragma unroll
        for (int i = 0; i < 4; i++)
          st[a][b][i] += bh[(a * 16 + kg * 4 + i) * 80 + b * 16 + lr];
    float inv[5];
    #pragma unroll
    for (int b = 0; b < 5; b++) {
      float mx = -1e30f;
      #pragma unroll
      for (int a = 0; a < 5; a++)
        #pragma unroll
        for (int i = 0; i < 4; i++) mx = fmaxf(mx, st[a][b][i]);
      mx = fmaxf(mx, __shfl_xor(mx, 16));
      mx = fmaxf(mx, __shfl_xor(mx, 32));
      float sm = 0.f;
      #pragma unroll
      for (int a = 0; a < 5; a++)
        #pragma unroll
        for (int i = 0; i < 4; i++) { float e = __expf(st[a][b][i] - mx); st[a][b][i] = e; sm += e; }
      sm += __shfl_xor(sm, 16); sm += __shfl_xor(sm, 32);
      inv[b] = 1.0f / sm;
    }
    #pragma unroll
    for (int a = 0; a < 5; a++)
      #pragma unroll
      for (int b = 0; b < 5; b++) {
        short4b pk;
        #pragma unroll
        for (int i = 0; i < 4; i++) pk[i] = f2bs(st[a][b][i] * inv[b]);
        *(short4b*)(P + (b * 16 + lr) * 104 + a * 16 + kg * 4) = pk;
      }
    const unsigned short* vh = (const unsigned short*)vT + hb;   // [32][80]
    short8 vf[2][3];
    #pragma unroll
    for (int dt = 0; dt < 2; dt++)
      #pragma unroll
      for (int ks = 0; ks < 3; ks++) {
        const int kb = ks * 32 + ((ks == 2 && kg >= 2) ? 0 : kg * 8);
        vf[dt][ks] = *(const short8*)(vh + (dt * 16 + lr) * 80 + kb);
      }
    f32x4 oc[5][2];
    #pragma unroll
    for (int b = 0; b < 5; b++)
      #pragma unroll
      for (int dt = 0; dt < 2; dt++) oc[b][dt] = (f32x4){0.f, 0.f, 0.f, 0.f};
    #pragma unroll
    for (int b = 0; b < 5; b++) {
      short8 pa[3];
      #pragma unroll
      for (int ks = 0; ks < 3; ks++)
        pa[ks] = *(const short8*)(P + (b * 16 + lr) * 104 + ks * 32 + kg * 8);
      #pragma unroll
      for (int dt = 0; dt < 2; dt++)
        #pragma unroll
        for (int ks = 0; ks < 3; ks++)
          oc[b][dt] = __builtin_amdgcn_mfma_f32_16x16x32_bf16(pa[ks], vf[dt][ks], oc[b][dt], 0, 0, 0);
    }
    unsigned short* ob = (unsigned short*)o + (size_t)win * NTOK * CDIM + head * 32;
    #pragma unroll
    for (int b = 0; b < 5; b++)
      #pragma unroll
      for (int i = 0; i < 4; i++) {
        const int row = b * 16 + kg * 4 + i;
        #pragma unroll
        for (int dt = 0; dt < 2; dt++)
          ob[(size_t)row * CDIM + dt * 16 + lr] = (unsigned short)f2bs(oc[b][dt][i]);
      }
  }
}

// ---------------- launcher ----------------
extern "C" void kernel_launch(void* const* d_in, const int* in_sizes, int n_in,
                              void* d_out, int out_size, void* d_ws, size_t ws_size,
                              hipStream_t stream) {
  const float* x       = (const float*)d_in[0];
  const float* n1g     = (const float*)d_in[1];
  const float* n1b     = (const float*)d_in[2];
  const float* qkv_w   = (const float*)d_in[3];
  const float* q_bias  = (const float*)d_in[4];
  const float* v_bias  = (const float*)d_in[5];
  const float* cpb_w1  = (const float*)d_in[6];
  const float* cpb_b1  = (const float*)d_in[7];
  const float* cpb_w2  = (const float*)d_in[8];
  const float* proj_w  = (const float*)d_in[9];
  const float* proj_b  = (const float*)d_in[10];
  const float* ls1     = (const float*)d_in[11];
  const float* n2g     = (const float*)d_in[12];
  const float* n2b     = (const float*)d_in[13];
  const float* glu_w   = (const float*)d_in[14];
  const float* glu_b   = (const float*)d_in[15];
  const float* out_w   = (const float*)d_in[16];
  const float* out_b   = (const float*)d_in[17];
  const float* ls2     = (const float*)d_in[18];
  float* out = (float*)d_out;

  char* ws = (char*)d_ws;
  bf16* r0     = (bf16*)(ws + R0_OFF);     // y1 -> vT -> y2
  bf16* q_buf  = (bf16*)(ws + Q_OFF);
  bf16* k_buf  = (bf16*)(ws + K_OFF);
  bf16* v_buf  = (bf16*)(ws + V_OFF);      // v -> O
  bf16* h_buf  = (bf16*)(ws + Q_OFF);      // h spans q..v after attention path done
  float* biasT = (float*)(ws + BIAS_OFF);
  bf16* wqkv   = (bf16*)(ws + WQKV_OFF);
  bf16* wproj  = (bf16*)(ws + WPROJ_OFF);
  bf16* wglu   = (bf16*)(ws + WGLU_OFF);
  bf16* wout   = (bf16*)(ws + WOUT_OFF);

  // weight casts f32 -> bf16
  cvt_f32_bf16<<<dim3((1152 * 384 + 255) / 256), 256, 0, stream>>>(qkv_w, wqkv, 1152 * 384);
  cvt_f32_bf16<<<dim3((384 * 384 + 255) / 256), 256, 0, stream>>>(proj_w, wproj, 384 * 384);
  cvt_f32_bf16<<<dim3((2048 * 384 + 255) / 256), 256, 0, stream>>>(glu_w, wglu, 2048 * 384);
  cvt_f32_bf16<<<dim3((384 * 1024 + 255) / 256), 256, 0, stream>>>(out_w, wout, 384 * 1024);

  // rel-pos bias table (transposed)
  cpb_bias_kernel<<<1, 256, 0, stream>>>(cpb_w1, cpb_b1, cpb_w2, biasT);

  // LN1 -> bf16, windowed row order (y1 in r0)
  ln_kernel<<<TOK / 4, 256, 0, stream>>>(x, n1g, n1b, r0, 1);

  // QKV GEMM (M=184320, N=1152, K=384): 720 x 9 tiles
  gemm_qkv_kernel<<<720 * 9, 512, 0, stream>>>(r0, wqkv, q_bias, v_bias, q_buf, k_buf, v_buf);

  // V transpose into r0 (y1 dead)
  vtrans_kernel<<<NWIN * HEADS, 64, 0, stream>>>(v_buf, r0);

  // MFMA attention; O -> v_buf (v dead)
  attn_kernel<<<NWIN, 256, 0, stream>>>(q_buf, k_buf, r0, biasT, v_buf);

  // proj GEMM + window-reverse + x1 = x + ls1*o -> d_out (fp32): 720 x 3 tiles
  gemm_proj_kernel<<<720 * 3, 512, 0, stream>>>(v_buf, wproj, proj_b, x, ls1, out);

  // LN2 (token-major) -> r0 as y2 (vT dead)
  ln_kernel<<<TOK / 4, 256, 0, stream>>>(out, n2g, n2b, r0, 0);

  // fused GLU GEMM -> h: 1440 x 8 tiles (BM=128)
  gemm_glu_kernel<<<1440 * 8, 512, 0, stream>>>(r0, wglu, glu_b, h_buf);

  // out GEMM (K=1024), d_out += ls2*(h@W^T + b): 720 x 3 tiles
  gemm_out_kernel<<<720 * 3, 512, 0, stream>>>(h_buf, wout, out_b, ls2, out);

  (void)in_sizes; (void)n_in; (void)out_size; (void)ws_size;
}